// Round 7
// baseline (568.418 us; speedup 1.0000x reference)
//
#include <hip/hip_runtime.h>

#define UNITS   114
#define SDIM    64
#define ACT     18
#define TSTEPS  64

// Globally-balanced bin-packed slots (placement identical to R4/R5):
//   rec:     E <= 704 edges, max in-degree <= 32. C=13/lane, <=2 posts/lane,
//            <=3 lanes/post. sensory: E == 512, max in-degree <= 20. C=9.
#define CR 13
#define CS 9
#define ER_CAP 704
#define MSTRIDE 24

#define LOG2E 1.4426950408889634f
#define EPS   1e-8f

typedef float v2f __attribute__((ext_vector_type(2)));
__device__ __forceinline__ v2f fma2(v2f a, v2f b, v2f c) {
  return __builtin_elementwise_fma(a, b, c);
}
__device__ __forceinline__ float bperm(int addr, float v) {
  return __int_as_float(__builtin_amdgcn_ds_bpermute(addr, __float_as_int(v)));
}
__device__ __forceinline__ float dperm(int addr, float v) {   // push: lane[addr>>2] <- v
  return __int_as_float(__builtin_amdgcn_ds_permute(addr, __float_as_int(v)));
}
// Wave-internal LDS phase separator (compiler fence + wave barrier, ~0 instr).
__device__ __forceinline__ void wsync() {
  __builtin_amdgcn_fence(__ATOMIC_ACQ_REL, "wavefront");
  __builtin_amdgcn_wave_barrier();
}
__device__ __forceinline__ int canonLane(int u) { return (u >= 64) ? (u - 64) : u; }

// k-th set bit of a 64-bit mask (k 0-based).
__device__ __forceinline__ int kthSetBit(unsigned long long m, int k) {
  int pos = 0;
#pragma unroll
  for (int ww = 32; ww >= 1; ww >>= 1) {
    const unsigned long long lowMask = ((1ull << ww) - 1ull);
    const int c = __popcll(m & lowMask);
    if (k >= c) { k -= c; m >>= ww; pos += ww; }
  }
  return pos;
}

// ---------------------------------------------------------------------------
// Build (unchanged from R5): 2 blocks (rec / sensory), parallel placement.
// ---------------------------------------------------------------------------
__global__ __launch_bounds__(64) void build_all(
    const float* __restrict__ w,  const float* __restrict__ mu,
    const float* __restrict__ sigma, const float* __restrict__ erev,
    const float* __restrict__ mask,
    const float* __restrict__ sw, const float* __restrict__ smu,
    const float* __restrict__ ssg, const float* __restrict__ serev,
    const float* __restrict__ smask,
    float4* __restrict__ recP4, float2* __restrict__ recP2, int* __restrict__ recAd,
    float4* __restrict__ senP4, float2* __restrict__ senP2, int* __restrict__ senAd,
    int* __restrict__ meta)
{
  const int l = threadIdx.x;
  __shared__ short ePre[ER_CAP], ePIdx[ER_CAP];
  __shared__ int deg[64], off[65];
  __shared__ int pLane[64], pF0[64], pRole[64];
  __shared__ int contIdx[64], contOwn[64], splitRole[64], split2[64], ownP[128];
  __shared__ int rcv[64];

  contIdx[l] = 0; contOwn[l] = 0; splitRole[l] = -1; split2[l] = 0;
  ownP[2*l] = -1; ownP[2*l+1] = -1;
  pLane[l] = 0; pF0[l] = 0; pRole[l] = 0;

  if (blockIdx.x == 0) {
    int d = 0;
    if (l < 50) for (int i = 18; i < UNITS; ++i) d += (mask[i*UNITS + l] != 0.f) ? 1 : 0;
    deg[l] = (l < 50) ? d : 0;
    __syncthreads();
    if (l == 0) { int a = 0; for (int j = 0; j < 64; ++j) { off[j] = a; a += deg[j]; } off[64] = a; }
    __syncthreads();
    if (l < 50) {
      int o = off[l];
      for (int i = 18; i < UNITS; ++i)
        if (mask[i*UNITS + l] != 0.f) { ePre[o] = (short)i; ePIdx[o] = (short)l; ++o; }
    }
    if (l == 0) {
      int lam = 0, f = 0, pc = 0;
      for (int p = 0; p < 50; ++p) {
        const int dd = deg[p];
        if (pc == 2 || f == CR || dd > 3*CR - f) { ++lam; f = 0; pc = 0; }
        if (lam > 63) lam = 63;
        pLane[p] = lam; pF0[p] = f; pRole[p] = pc;
        ownP[2*lam + pc] = p;
        const int owner = lam, role = pc; ++pc;
        const int take = dd < (CR - f) ? dd : (CR - f);
        f += take; int rem = dd - take;
        if (rem > 0) {
          splitRole[owner] = role; split2[owner] = (rem > CR) ? 1 : 0;
          ++lam; if (lam > 63) lam = 63; contIdx[lam] = 1; contOwn[lam] = owner; pc = 1;
          const int t2 = rem < CR ? rem : CR; f = t2; rem -= t2;
          if (rem > 0) { ++lam; if (lam > 63) lam = 63; contIdx[lam] = 2; contOwn[lam] = owner; pc = 1; f = rem; }
        }
      }
    }
    __syncthreads();
    int dA = (contIdx[l] == 1) ? contOwn[l] : -1;
    int dB = (contIdx[l] == 2) ? contOwn[l] : -1;
    rcv[l] = 0; __syncthreads();
    if (dA >= 0) rcv[dA] = 1;
    __syncthreads();
    { const unsigned long long rM = __ballot(rcv[l] != 0), dM = __ballot(dA < 0);
      if (dA < 0) dA = kthSetBit(~rM, __popcll(dM & ((1ull << l) - 1ull))); }
    __syncthreads();
    rcv[l] = 0; __syncthreads();
    if (dB >= 0) rcv[dB] = 1;
    __syncthreads();
    { const unsigned long long rM = __ballot(rcv[l] != 0), dM = __ballot(dB < 0);
      if (dB < 0) dB = kthSetBit(~rM, __popcll(dM & ((1ull << l) - 1ull))); }
    {
      int* M = meta + l * MSTRIDE;
      M[0] = dA * 4; M[1] = dB * 4;
      const float s1A = (splitRole[l] == 0) ? 1.f : 0.f, s1B = (splitRole[l] == 1) ? 1.f : 0.f;
      M[2] = __float_as_int(s1A); M[3] = __float_as_int(s1B);
      const float s2 = split2[l] ? 1.f : 0.f;
      M[4] = __float_as_int(s1A * s2); M[5] = __float_as_int(s1B * s2);
      const int uA = ownP[2*l], uB = ownP[2*l+1];
      M[6] = ((uA >= 0) ? uA : 128 + l) * 4;
      M[7] = ((uB >= 0) ? uB : 192 + l) * 4;
      M[8] = (uA >= 0) ? uA : 0;
      M[9] = (uB >= 0) ? uB : 0;
    }
    for (int t = l; t < CR*64; t += 64) {
      recP4[t] = make_float4(0.f,0.f,0.f,0.f); recP2[t] = make_float2(0.f,0.f); recAd[t] = 0;
    }
    __syncthreads();
    {
      const int E = off[64];
      for (int e = l; e < E; e += 64) {
        const int pre = ePre[e], pj = ePIdx[e];
        const int r  = e - off[pj];
        const int dd = deg[pj], f0 = pF0[pj], role0 = pRole[pj];
        const int take = dd < (CR - f0) ? dd : (CR - f0);
        int lane = pLane[pj], slot, role;
        if (r < take)            { slot = f0 + r;        role = role0; }
        else if (r < take + CR)  { lane += 1; slot = r - take;      role = 0; }
        else                     { lane += 2; slot = r - take - CR; role = 0; }
        if (lane > 63) lane = 63;
        const int idx = pre * UNITS + pj;
        const float sg = sigma[idx];
        const float nsgl = -sg * LOG2E, msl = mu[idx] * sg * LOG2E;
        const float wd = w[idx], wn = wd * erev[idx];
        const int tt = slot * 64 + lane;
        recP4[tt] = make_float4(nsgl, msl, role ? 0.f : wn, role ? 0.f : wd);
        recP2[tt] = role ? make_float2(wn, wd) : make_float2(0.f, 0.f);
        recAd[tt] = pre * 4;
      }
    }
  } else {
    int d = 0;
    { const int col = 50 + l; for (int i = 0; i < SDIM; ++i) d += (smask[i*UNITS + col] != 0.f) ? 1 : 0; }
    deg[l] = d;
    __syncthreads();
    if (l == 0) { int a = 0; for (int j = 0; j < 64; ++j) { off[j] = a; a += deg[j]; } off[64] = a; }
    __syncthreads();
    {
      int o = off[l]; const int col = 50 + l;
      for (int i = 0; i < SDIM; ++i)
        if (smask[i*UNITS + col] != 0.f) { ePre[o] = (short)i; ePIdx[o] = (short)l; ++o; }
    }
    if (l == 0) {
      int lam = 0, f = 0, pc = 0;
      for (int p = 0; p < 64; ++p) {
        const int dd = deg[p];
        if (pc == 2 || f == CS || dd > 3*CS - f) { ++lam; f = 0; pc = 0; }
        if (lam > 63) lam = 63;
        pLane[p] = lam; pF0[p] = f; pRole[p] = pc;
        ownP[2*lam + pc] = p;
        const int owner = lam, role = pc; ++pc;
        const int take = dd < (CS - f) ? dd : (CS - f);
        f += take; int rem = dd - take;
        if (rem > 0) {
          splitRole[owner] = role; split2[owner] = (rem > CS) ? 1 : 0;
          ++lam; if (lam > 63) lam = 63; contIdx[lam] = 1; contOwn[lam] = owner; pc = 1;
          const int t2 = rem < CS ? rem : CS; f = t2; rem -= t2;
          if (rem > 0) { ++lam; if (lam > 63) lam = 63; contIdx[lam] = 2; contOwn[lam] = owner; pc = 1; f = rem; }
        }
      }
    }
    __syncthreads();
    int dA = (contIdx[l] == 1) ? contOwn[l] : -1;
    int dB = (contIdx[l] == 2) ? contOwn[l] : -1;
    rcv[l] = 0; __syncthreads();
    if (dA >= 0) rcv[dA] = 1;
    __syncthreads();
    { const unsigned long long rM = __ballot(rcv[l] != 0), dM = __ballot(dA < 0);
      if (dA < 0) dA = kthSetBit(~rM, __popcll(dM & ((1ull << l) - 1ull))); }
    __syncthreads();
    rcv[l] = 0; __syncthreads();
    if (dB >= 0) rcv[dB] = 1;
    __syncthreads();
    { const unsigned long long rM = __ballot(rcv[l] != 0), dM = __ballot(dB < 0);
      if (dB < 0) dB = kthSetBit(~rM, __popcll(dM & ((1ull << l) - 1ull))); }
    __syncthreads();
    int rA = (ownP[2*l]   >= 0) ? canonLane(50 + ownP[2*l])   : -1;
    int rB = (ownP[2*l+1] >= 0) ? canonLane(50 + ownP[2*l+1]) : -1;
    rcv[l] = 0; __syncthreads();
    if (rA >= 0) rcv[rA] = 1;
    __syncthreads();
    const int isRcvA = rcv[l];
    { const unsigned long long rM = __ballot(isRcvA != 0), dM = __ballot(rA < 0);
      if (rA < 0) rA = kthSetBit(~rM, __popcll(dM & ((1ull << l) - 1ull))); }
    __syncthreads();
    rcv[l] = 0; __syncthreads();
    if (rB >= 0) rcv[rB] = 1;
    __syncthreads();
    { const unsigned long long rM = __ballot(rcv[l] != 0), dM = __ballot(rB < 0);
      if (rB < 0) rB = kthSetBit(~rM, __popcll(dM & ((1ull << l) - 1ull))); }
    {
      int* M = meta + l * MSTRIDE;
      M[10] = dA * 4; M[11] = dB * 4;
      const float s1A = (splitRole[l] == 0) ? 1.f : 0.f, s1B = (splitRole[l] == 1) ? 1.f : 0.f;
      M[12] = __float_as_int(s1A); M[13] = __float_as_int(s1B);
      const float s2 = split2[l] ? 1.f : 0.f;
      M[14] = __float_as_int(s1A * s2); M[15] = __float_as_int(s1B * s2);
      M[16] = rA * 4; M[17] = rB * 4;
      M[18] = __float_as_int(isRcvA ? 1.f : 0.f);
      M[19] = __float_as_int(isRcvA ? 0.f : 1.f);
      const int pA = ownP[2*l], pB = ownP[2*l+1];
      M[20] = (pA >= 0) ? 50 + pA : 0;
      M[21] = (pB >= 0) ? 50 + pB : 0;
    }
    for (int t = l; t < CS*64; t += 64) {
      senP4[t] = make_float4(0.f,0.f,0.f,0.f); senP2[t] = make_float2(0.f,0.f); senAd[t] = 0;
    }
    __syncthreads();
    {
      const int E = off[64];
      for (int e = l; e < E; e += 64) {
        const int pre = ePre[e], pj = ePIdx[e];
        const int r  = e - off[pj];
        const int dd = deg[pj], f0 = pF0[pj], role0 = pRole[pj];
        const int take = dd < (CS - f0) ? dd : (CS - f0);
        int lane = pLane[pj], slot, role;
        if (r < take)            { slot = f0 + r;        role = role0; }
        else if (r < take + CS)  { lane += 1; slot = r - take;      role = 0; }
        else                     { lane += 2; slot = r - take - CS; role = 0; }
        if (lane > 63) lane = 63;
        const int col = 50 + pj;
        const int idx = pre * UNITS + col;
        const float sg = ssg[idx];
        const float nsgl = -sg * LOG2E, msl = smu[idx] * sg * LOG2E;
        const float wd = sw[idx], wn = wd * serev[idx];
        const int tt = slot * 64 + lane;
        senP4[tt] = make_float4(nsgl, msl, role ? 0.f : wn, role ? 0.f : wd);
        senP2[tt] = role ? make_float2(wn, wd) : make_float2(0.f, 0.f);
        senAd[tt] = pre * 4;
      }
    }
  }
}

// ---------------------------------------------------------------------------
// Shared sensory evaluation: balanced slots, quad-shared rcp, pk accumulators,
// parallel merge rounds, route to canonical lanes. Returns (aI, bI).
// ---------------------------------------------------------------------------
__device__ __forceinline__ float2 sensory_eval(
    const float xi,
    const float* sNS, const float* sMS, const v2f* sWA, const v2f* sWB,
    const int* sad,
    int sPush1, int sPush2, v2f gS1A, v2f gS1B, v2f gS2A, v2f gS2B,
    int sRtA, int sRtB, float sRndA, float sRndB,
    float cmSA, float glvSA, float cgSA, float cmSB, float glvSB, float cgSB)
{
  float u[CS];
#pragma unroll
  for (int s = 0; s < CS; ++s) {
    float z = fmaf(bperm(sad[s], xi), sNS[s], sMS[s]);
    z = fminf(z, 30.f);
    u[s] = 1.f + __builtin_amdgcn_exp2f(z);
  }
  float sg[CS];
#pragma unroll
  for (int q = 0; q < 2; ++q) {
    const int s0 = 4*q;
    const float p01 = u[s0]*u[s0+1], p23 = u[s0+2]*u[s0+3];
    const float r = __builtin_amdgcn_rcpf(p01*p23);
    const float t23 = p23*r, t01 = p01*r;
    sg[s0]   = u[s0+1]*t23; sg[s0+1] = u[s0]*t23;
    sg[s0+2] = u[s0+3]*t01; sg[s0+3] = u[s0+2]*t01;
  }
  sg[8] = __builtin_amdgcn_rcpf(u[8]);
  v2f cA = {0.f, 0.f}, cB = {0.f, 0.f};
#pragma unroll
  for (int s = 0; s < CS; ++s) {
    const v2f s2 = {sg[s], sg[s]};
    cA = fma2(sWA[s], s2, cA);
    cB = fma2(sWB[s], s2, cB);
  }
  const v2f m1 = {dperm(sPush1, cA.x), dperm(sPush1, cA.y)};
  const v2f m2 = {dperm(sPush2, cA.x), dperm(sPush2, cA.y)};
  v2f tA = fma2(gS1A, m1, cA); tA = fma2(gS2A, m2, tA);
  v2f tB = fma2(gS1B, m1, cB); tB = fma2(gS2B, m2, tB);
  const float rdA = __builtin_amdgcn_rcpf(cgSA + tA.y);
  const float aA = cmSA * rdA, bA = (glvSA + tA.x) * rdA;
  const float rdB = __builtin_amdgcn_rcpf(cgSB + tB.y);
  const float aB = cmSB * rdB, bB = (glvSB + tB.x) * rdB;
  const float ra1 = dperm(sRtA, aA), rb1 = dperm(sRtA, bA);
  const float ra2 = dperm(sRtB, aB), rb2 = dperm(sRtB, bB);
  return make_float2(sRndA*ra1 + sRndB*ra2, sRndA*rb1 + sRndB*rb2);
}

// ---------------------------------------------------------------------------
// Sensory precompute: one wave per (b,t) -- time-parallel, full occupancy.
// Writes (aI,bI) per lane to sAB.
// ---------------------------------------------------------------------------
__global__ __launch_bounds__(256) void sens_pre(
    const float* __restrict__ obs, const float* __restrict__ input_w,
    const float* __restrict__ input_b,
    const float* __restrict__ gleak, const float* __restrict__ vleak,
    const float* __restrict__ cm,
    const float4* __restrict__ senP4, const float2* __restrict__ senP2,
    const int* __restrict__ senAd, const int* __restrict__ meta,
    float2* __restrict__ sAB, int B)
{
  const int l = threadIdx.x & 63;
  const int wv = blockIdx.x * 4 + (threadIdx.x >> 6);
  const int b = wv >> 6, t = wv & 63;
  if (b >= B) return;

  float sNS[CS], sMS[CS]; v2f sWA[CS], sWB[CS]; int sad[CS];
#pragma unroll
  for (int s = 0; s < CS; ++s) {
    const float4 p4 = senP4[s*64 + l]; const float2 p2 = senP2[s*64 + l];
    sNS[s] = p4.x; sMS[s] = p4.y; sWA[s] = (v2f){p4.z, p4.w};
    sWB[s] = (v2f){p2.x, p2.y}; sad[s] = senAd[s*64 + l];
  }
  const int* M = meta + l * MSTRIDE;
  const int   sPush1 = M[10], sPush2 = M[11];
  const float sS1A = __int_as_float(M[12]), sS1B = __int_as_float(M[13]);
  const float sS2A = __int_as_float(M[14]), sS2B = __int_as_float(M[15]);
  const int   sRtA = M[16], sRtB = M[17];
  const float sRndA = __int_as_float(M[18]), sRndB = __int_as_float(M[19]);
  const int   sUA = M[20], sUB = M[21];
  const float cmSA = cm[sUA]*6.f, glvSA = gleak[sUA]*vleak[sUA], cgSA = cm[sUA]*6.f + gleak[sUA] + EPS;
  const float cmSB = cm[sUB]*6.f, glvSB = gleak[sUB]*vleak[sUB], cgSB = cm[sUB]*6.f + gleak[sUB] + EPS;

  const float xi = obs[((size_t)b*TSTEPS + t)*SDIM + l] * input_w[l] + input_b[l];
  const float2 ab = sensory_eval(xi, sNS, sMS, sWA, sWB, sad,
      sPush1, sPush2, (v2f){sS1A,sS1A}, (v2f){sS1B,sS1B}, (v2f){sS2A,sS2A}, (v2f){sS2B,sS2B},
      sRtA, sRtB, sRndA, sRndB, cmSA, glvSA, cgSA, cmSB, glvSB, cgSB);
  sAB[((size_t)b*TSTEPS + t)*64 + l] = ab;
}

// ---------------------------------------------------------------------------
// Run kernel: one wave per batch element. SENS=1 reads precomputed (aI,bI);
// SENS=0 computes sensory inline. Quad-shared rcp + pk-fma in the unfolds.
// ---------------------------------------------------------------------------
template <int SENS>
__global__ __launch_bounds__(64, 2) void ltc_run(
    const float* __restrict__ obs,     const float* __restrict__ hidden,
    const float* __restrict__ input_w, const float* __restrict__ input_b,
    const float* __restrict__ gleak,   const float* __restrict__ vleak,
    const float* __restrict__ cm,
    const float* __restrict__ q_w1, const float* __restrict__ q_b1,
    const float* __restrict__ q_w2, const float* __restrict__ q_b2,
    const float4* __restrict__ recP4, const float2* __restrict__ recP2,
    const int* __restrict__ recAd,
    const float4* __restrict__ senP4, const float2* __restrict__ senP2,
    const int* __restrict__ senAd,
    const int* __restrict__ meta, const float2* __restrict__ sAB,
    float* __restrict__ out, int B)
{
  const int l = threadIdx.x, b = blockIdx.x;
  __shared__ float mirror[256];   // [0..113] units, [128..255] scratch sinks
  char* mbase = (char*)mirror;

  float rNS[CR], rMS[CR]; v2f rWA[CR], rWB[CR]; int rad[CR];
#pragma unroll
  for (int s = 0; s < CR; ++s) {
    const float4 p4 = recP4[s*64 + l]; const float2 p2 = recP2[s*64 + l];
    rNS[s] = p4.x; rMS[s] = p4.y; rWA[s] = (v2f){p4.z, p4.w};
    rWB[s] = (v2f){p2.x, p2.y}; rad[s] = recAd[s*64 + l];
  }
  const int* M = meta + l * MSTRIDE;
  const int   rPush1 = M[0], rPush2 = M[1];
  const v2f gR1A = {__int_as_float(M[2]), __int_as_float(M[2])};
  const v2f gR1B = {__int_as_float(M[3]), __int_as_float(M[3])};
  const v2f gR2A = {__int_as_float(M[4]), __int_as_float(M[4])};
  const v2f gR2B = {__int_as_float(M[5]), __int_as_float(M[5])};
  const int   rWrA = M[6], rWrB = M[7], rUA = M[8], rUB = M[9];

  // sensory setup only for the inline path
  float sNS[CS], sMS[CS]; v2f sWA[CS], sWB[CS]; int sad[CS];
  int sPush1=0, sPush2=0, sRtA=0, sRtB=0;
  float sS1A=0, sS1B=0, sS2A=0, sS2B=0, sRndA=0, sRndB=0;
  float cmSA=0, glvSA=0, cgSA=0, cmSB=0, glvSB=0, cgSB=0;
  if (SENS == 0) {
#pragma unroll
    for (int s = 0; s < CS; ++s) {
      const float4 p4 = senP4[s*64 + l]; const float2 p2 = senP2[s*64 + l];
      sNS[s] = p4.x; sMS[s] = p4.y; sWA[s] = (v2f){p4.z, p4.w};
      sWB[s] = (v2f){p2.x, p2.y}; sad[s] = senAd[s*64 + l];
    }
    sPush1 = M[10]; sPush2 = M[11];
    sS1A = __int_as_float(M[12]); sS1B = __int_as_float(M[13]);
    sS2A = __int_as_float(M[14]); sS2B = __int_as_float(M[15]);
    sRtA = M[16]; sRtB = M[17];
    sRndA = __int_as_float(M[18]); sRndB = __int_as_float(M[19]);
    const int sUA = M[20], sUB = M[21];
    cmSA = cm[sUA]*6.f; glvSA = gleak[sUA]*vleak[sUA]; cgSA = cm[sUA]*6.f + gleak[sUA] + EPS;
    cmSB = cm[sUB]*6.f; glvSB = gleak[sUB]*vleak[sUB]; cgSB = cm[sUB]*6.f + gleak[sUB] + EPS;
  }

  const float cmA = cm[rUA]*6.f, glvA = gleak[rUA]*vleak[rUA], cgA = cm[rUA]*6.f + gleak[rUA] + EPS;
  const float cmB = cm[rUB]*6.f, glvB = gleak[rUB]*vleak[rUB], cgB = cm[rUB]*6.f + gleak[rUB] + EPS;

  const int  iUnit = (l < 50) ? 64 + l : l;
  const int  iWr   = iUnit * 4;
  float vIn = hidden[(size_t)b*UNITS + iUnit];
  float vPA = hidden[(size_t)b*UNITS + rUA];
  float vPB = hidden[(size_t)b*UNITS + rUB];

  mirror[l] = hidden[(size_t)b*UNITS + l];
  if (l < 50) mirror[64 + l] = hidden[(size_t)b*UNITS + 64 + l];

  const float iw = (SENS == 0) ? input_w[l] : 0.f;
  const float ibv = (SENS == 0) ? input_b[l] : 0.f;
  const float* ob = obs + (size_t)b*(TSTEPS*SDIM) + l;
  float xr = (SENS == 0) ? ob[0] : 0.f;

  const float2* sBase = sAB + (size_t)b*TSTEPS*64 + l;
  float2 abC, abN;
  if (SENS == 1) abC = sBase[0];

  for (int t = 0; t < TSTEPS; ++t) {
    float aI, bI;
    if (SENS == 1) {
      aI = abC.x; bI = abC.y;
      if (t + 1 < TSTEPS) abN = sBase[(t + 1) * 64];
    } else {
      const float xi = xr * iw + ibv;
      if (t + 1 < TSTEPS) xr = ob[(t + 1) * SDIM];
      const float2 ab = sensory_eval(xi, sNS, sMS, sWA, sWB, sad,
          sPush1, sPush2, (v2f){sS1A,sS1A}, (v2f){sS1B,sS1B},
          (v2f){sS2A,sS2A}, (v2f){sS2B,sS2B},
          sRtA, sRtB, sRndA, sRndB, cmSA, glvSA, cgSA, cmSB, glvSB, cgSB);
      aI = ab.x; bI = ab.y;
    }

    // ---- 6 ODE unfolds ----
#pragma unroll 1
    for (int u_ = 0; u_ < 6; ++u_) {
      wsync();
      float u[CR];
#pragma unroll
      for (int s = 0; s < CR; ++s) {
        const float pv = *(const float*)(mbase + rad[s]);
        float z = fmaf(pv, rNS[s], rMS[s]);
        z = fminf(z, 30.f);
        u[s] = 1.f + __builtin_amdgcn_exp2f(z);
      }
      float sg[CR];
#pragma unroll
      for (int q = 0; q < 3; ++q) {
        const int s0 = 4*q;
        const float p01 = u[s0]*u[s0+1], p23 = u[s0+2]*u[s0+3];
        const float r = __builtin_amdgcn_rcpf(p01*p23);
        const float t23 = p23*r, t01 = p01*r;
        sg[s0]   = u[s0+1]*t23; sg[s0+1] = u[s0]*t23;
        sg[s0+2] = u[s0+3]*t01; sg[s0+3] = u[s0+2]*t01;
      }
      sg[12] = __builtin_amdgcn_rcpf(u[12]);
      v2f aA = {0.f, 0.f}, aB = {0.f, 0.f};
#pragma unroll
      for (int s = 0; s < CR; ++s) {
        const v2f s2 = {sg[s], sg[s]};
        aA = fma2(rWA[s], s2, aA);
        aB = fma2(rWB[s], s2, aB);
      }
      // parallel merge rounds (both push the pre-merge value)
      const v2f m1 = {dperm(rPush1, aA.x), dperm(rPush1, aA.y)};
      const v2f m2 = {dperm(rPush2, aA.x), dperm(rPush2, aA.y)};
      v2f tA = fma2(gR1A, m1, aA); tA = fma2(gR2A, m2, tA);
      v2f tB = fma2(gR1B, m1, aB); tB = fma2(gR2B, m2, tB);

      vPA = (fmaf(cmA, vPA, glvA) + tA.x) * __builtin_amdgcn_rcpf(cgA + tA.y);
      vPB = (fmaf(cmB, vPB, glvB) + tB.x) * __builtin_amdgcn_rcpf(cgB + tB.y);
      vIn = fmaf(aI, vIn, bI);
      wsync();
      *(float*)(mbase + rWrA) = vPA;
      *(float*)(mbase + rWrB) = vPB;
      *(float*)(mbase + iWr)  = vIn;
    }
    if (SENS == 1) abC = abN;
  }
  wsync();

  // ---- outputs: h then Q head ----
  float* __restrict__ outH = out + (size_t)B * ACT;
  outH[(size_t)b*UNITS + l] = mirror[l];
  if (l < 50) outH[(size_t)b*UNITS + 64 + l] = mirror[64 + l];

  const int j2 = (l < 50) ? 64 + l : l;
  float h1 = q_b1[l], h2 = q_b1[j2];
  for (int i = 0; i < UNITS; ++i) {
    const float hv = mirror[i];
    h1 = fmaf(hv, q_w1[i*UNITS + l],  h1);
    h2 = fmaf(hv, q_w1[i*UNITS + j2], h2);
  }
  h1 = fmaxf(h1, 0.f); h2 = fmaxf(h2, 0.f);
  wsync();
  mirror[l] = h1;
  if (l < 50) mirror[64 + l] = h2;
  wsync();
  if (l < ACT) {
    float q = q_b2[l];
    for (int i = 0; i < UNITS; ++i) q = fmaf(mirror[i], q_w2[i*ACT + l], q);
    out[(size_t)b*ACT + l] = q;
  }
}

extern "C" void kernel_launch(void* const* d_in, const int* in_sizes, int n_in,
                              void* d_out, int out_size, void* d_ws, size_t ws_size,
                              hipStream_t stream)
{
  const float* obs           = (const float*)d_in[0];
  const float* hidden        = (const float*)d_in[1];
  const float* input_w       = (const float*)d_in[2];
  const float* input_b       = (const float*)d_in[3];
  const float* sensory_w     = (const float*)d_in[4];
  const float* sensory_mu    = (const float*)d_in[5];
  const float* sensory_sigma = (const float*)d_in[6];
  const float* sensory_erev  = (const float*)d_in[7];
  const float* sensory_mask  = (const float*)d_in[8];
  const float* w             = (const float*)d_in[9];
  const float* mu            = (const float*)d_in[10];
  const float* sigma         = (const float*)d_in[11];
  const float* erev          = (const float*)d_in[12];
  const float* mask          = (const float*)d_in[13];
  const float* gleak         = (const float*)d_in[14];
  const float* vleak         = (const float*)d_in[15];
  const float* cm            = (const float*)d_in[16];
  const float* q_w1          = (const float*)d_in[17];
  const float* q_b1          = (const float*)d_in[18];
  const float* q_w2          = (const float*)d_in[19];
  const float* q_b2          = (const float*)d_in[20];

  char* ws = (char*)d_ws;
  float4* recP4 = (float4*)(ws);            // 13*64*16 = 13312
  float2* recP2 = (float2*)(ws + 13312);    // 13*64*8  = 6656  -> 19968
  int*    recAd = (int*)   (ws + 19968);    // 13*64*4  = 3328  -> 23296
  float4* senP4 = (float4*)(ws + 23296);    // 9*64*16  = 9216  -> 32512
  float2* senP2 = (float2*)(ws + 32512);    // 9*64*8   = 4608  -> 37120
  int*    senAd = (int*)   (ws + 37120);    // 9*64*4   = 2304  -> 39424
  int*    meta  = (int*)   (ws + 39424);    // 64*24*4  = 6144  -> 45568
  const size_t sABoff = 65536;
  float2* sAB   = (float2*)(ws + sABoff);

  const int B = in_sizes[0] / (TSTEPS * SDIM);
  const size_t need = sABoff + (size_t)B * TSTEPS * 64 * sizeof(float2);

  build_all<<<2, 64, 0, stream>>>(
      w, mu, sigma, erev, mask,
      sensory_w, sensory_mu, sensory_sigma, sensory_erev, sensory_mask,
      recP4, recP2, recAd, senP4, senP2, senAd, meta);

  if (ws_size >= need) {
    sens_pre<<<B * 16, 256, 0, stream>>>(
        obs, input_w, input_b, gleak, vleak, cm,
        senP4, senP2, senAd, meta, sAB, B);
    ltc_run<1><<<B, 64, 0, stream>>>(
        obs, hidden, input_w, input_b, gleak, vleak, cm,
        q_w1, q_b1, q_w2, q_b2,
        recP4, recP2, recAd, senP4, senP2, senAd, meta, sAB,
        (float*)d_out, B);
  } else {
    ltc_run<0><<<B, 64, 0, stream>>>(
        obs, hidden, input_w, input_b, gleak, vleak, cm,
        q_w1, q_b1, q_w2, q_b2,
        recP4, recP2, recAd, senP4, senP2, senAd, meta, sAB,
        (float*)d_out, B);
  }
}

// Round 8
// 404.176 us; speedup vs baseline: 1.4064x; 1.4064x over previous
//
#include <hip/hip_runtime.h>

#define UNITS   114
#define SDIM    64
#define ACT     18
#define TSTEPS  64

// Globally-balanced bin-packed slots (placement identical to R4/R5):
//   rec:     E <= 704 edges, max in-degree <= 32. C=13/lane, <=2 posts/lane,
//            <=3 lanes/post. sensory: E == 512, max in-degree <= 20. C=9.
#define CR 13
#define CS 9
#define ER_CAP 704
#define MSTRIDE 24

#define LOG2E 1.4426950408889634f
#define EPS   1e-8f

typedef float v2f __attribute__((ext_vector_type(2)));
__device__ __forceinline__ v2f fma2(v2f a, v2f b, v2f c) {
  return __builtin_elementwise_fma(a, b, c);
}
__device__ __forceinline__ float bperm(int addr, float v) {
  return __int_as_float(__builtin_amdgcn_ds_bpermute(addr, __float_as_int(v)));
}
__device__ __forceinline__ float dperm(int addr, float v) {   // push: lane[addr>>2] <- v
  return __int_as_float(__builtin_amdgcn_ds_permute(addr, __float_as_int(v)));
}
// Wave-internal LDS phase separator (compiler fence + wave barrier, ~0 instr).
__device__ __forceinline__ void wsync() {
  __builtin_amdgcn_fence(__ATOMIC_ACQ_REL, "wavefront");
  __builtin_amdgcn_wave_barrier();
}
__device__ __forceinline__ int canonLane(int u) { return (u >= 64) ? (u - 64) : u; }

// k-th set bit of a 64-bit mask (k 0-based).
__device__ __forceinline__ int kthSetBit(unsigned long long m, int k) {
  int pos = 0;
#pragma unroll
  for (int ww = 32; ww >= 1; ww >>= 1) {
    const unsigned long long lowMask = ((1ull << ww) - 1ull);
    const int c = __popcll(m & lowMask);
    if (k >= c) { k -= c; m >>= ww; pos += ww; }
  }
  return pos;
}

// ---------------------------------------------------------------------------
// Build (unchanged, proven): 2 blocks (rec / sensory), parallel placement.
// ---------------------------------------------------------------------------
__global__ __launch_bounds__(64) void build_all(
    const float* __restrict__ w,  const float* __restrict__ mu,
    const float* __restrict__ sigma, const float* __restrict__ erev,
    const float* __restrict__ mask,
    const float* __restrict__ sw, const float* __restrict__ smu,
    const float* __restrict__ ssg, const float* __restrict__ serev,
    const float* __restrict__ smask,
    float4* __restrict__ recP4, float2* __restrict__ recP2, int* __restrict__ recAd,
    float4* __restrict__ senP4, float2* __restrict__ senP2, int* __restrict__ senAd,
    int* __restrict__ meta)
{
  const int l = threadIdx.x;
  __shared__ short ePre[ER_CAP], ePIdx[ER_CAP];
  __shared__ int deg[64], off[65];
  __shared__ int pLane[64], pF0[64], pRole[64];
  __shared__ int contIdx[64], contOwn[64], splitRole[64], split2[64], ownP[128];
  __shared__ int rcv[64];

  contIdx[l] = 0; contOwn[l] = 0; splitRole[l] = -1; split2[l] = 0;
  ownP[2*l] = -1; ownP[2*l+1] = -1;
  pLane[l] = 0; pF0[l] = 0; pRole[l] = 0;

  if (blockIdx.x == 0) {
    int d = 0;
    if (l < 50) for (int i = 18; i < UNITS; ++i) d += (mask[i*UNITS + l] != 0.f) ? 1 : 0;
    deg[l] = (l < 50) ? d : 0;
    __syncthreads();
    if (l == 0) { int a = 0; for (int j = 0; j < 64; ++j) { off[j] = a; a += deg[j]; } off[64] = a; }
    __syncthreads();
    if (l < 50) {
      int o = off[l];
      for (int i = 18; i < UNITS; ++i)
        if (mask[i*UNITS + l] != 0.f) { ePre[o] = (short)i; ePIdx[o] = (short)l; ++o; }
    }
    if (l == 0) {
      int lam = 0, f = 0, pc = 0;
      for (int p = 0; p < 50; ++p) {
        const int dd = deg[p];
        if (pc == 2 || f == CR || dd > 3*CR - f) { ++lam; f = 0; pc = 0; }
        if (lam > 63) lam = 63;
        pLane[p] = lam; pF0[p] = f; pRole[p] = pc;
        ownP[2*lam + pc] = p;
        const int owner = lam, role = pc; ++pc;
        const int take = dd < (CR - f) ? dd : (CR - f);
        f += take; int rem = dd - take;
        if (rem > 0) {
          splitRole[owner] = role; split2[owner] = (rem > CR) ? 1 : 0;
          ++lam; if (lam > 63) lam = 63; contIdx[lam] = 1; contOwn[lam] = owner; pc = 1;
          const int t2 = rem < CR ? rem : CR; f = t2; rem -= t2;
          if (rem > 0) { ++lam; if (lam > 63) lam = 63; contIdx[lam] = 2; contOwn[lam] = owner; pc = 1; f = rem; }
        }
      }
    }
    __syncthreads();
    int dA = (contIdx[l] == 1) ? contOwn[l] : -1;
    int dB = (contIdx[l] == 2) ? contOwn[l] : -1;
    rcv[l] = 0; __syncthreads();
    if (dA >= 0) rcv[dA] = 1;
    __syncthreads();
    { const unsigned long long rM = __ballot(rcv[l] != 0), dM = __ballot(dA < 0);
      if (dA < 0) dA = kthSetBit(~rM, __popcll(dM & ((1ull << l) - 1ull))); }
    __syncthreads();
    rcv[l] = 0; __syncthreads();
    if (dB >= 0) rcv[dB] = 1;
    __syncthreads();
    { const unsigned long long rM = __ballot(rcv[l] != 0), dM = __ballot(dB < 0);
      if (dB < 0) dB = kthSetBit(~rM, __popcll(dM & ((1ull << l) - 1ull))); }
    {
      int* M = meta + l * MSTRIDE;
      M[0] = dA * 4; M[1] = dB * 4;
      const float s1A = (splitRole[l] == 0) ? 1.f : 0.f, s1B = (splitRole[l] == 1) ? 1.f : 0.f;
      M[2] = __float_as_int(s1A); M[3] = __float_as_int(s1B);
      const float s2 = split2[l] ? 1.f : 0.f;
      M[4] = __float_as_int(s1A * s2); M[5] = __float_as_int(s1B * s2);
      const int uA = ownP[2*l], uB = ownP[2*l+1];
      M[6] = ((uA >= 0) ? uA : 128 + l) * 4;
      M[7] = ((uB >= 0) ? uB : 192 + l) * 4;
      M[8] = (uA >= 0) ? uA : 0;
      M[9] = (uB >= 0) ? uB : 0;
    }
    for (int t = l; t < CR*64; t += 64) {
      recP4[t] = make_float4(0.f,0.f,0.f,0.f); recP2[t] = make_float2(0.f,0.f); recAd[t] = 0;
    }
    __syncthreads();
    {
      const int E = off[64];
      for (int e = l; e < E; e += 64) {
        const int pre = ePre[e], pj = ePIdx[e];
        const int r  = e - off[pj];
        const int dd = deg[pj], f0 = pF0[pj], role0 = pRole[pj];
        const int take = dd < (CR - f0) ? dd : (CR - f0);
        int lane = pLane[pj], slot, role;
        if (r < take)            { slot = f0 + r;        role = role0; }
        else if (r < take + CR)  { lane += 1; slot = r - take;      role = 0; }
        else                     { lane += 2; slot = r - take - CR; role = 0; }
        if (lane > 63) lane = 63;
        const int idx = pre * UNITS + pj;
        const float sg = sigma[idx];
        const float nsgl = -sg * LOG2E, msl = mu[idx] * sg * LOG2E;
        const float wd = w[idx], wn = wd * erev[idx];
        const int tt = slot * 64 + lane;
        recP4[tt] = make_float4(nsgl, msl, role ? 0.f : wn, role ? 0.f : wd);
        recP2[tt] = role ? make_float2(wn, wd) : make_float2(0.f, 0.f);
        recAd[tt] = pre * 4;
      }
    }
  } else {
    int d = 0;
    { const int col = 50 + l; for (int i = 0; i < SDIM; ++i) d += (smask[i*UNITS + col] != 0.f) ? 1 : 0; }
    deg[l] = d;
    __syncthreads();
    if (l == 0) { int a = 0; for (int j = 0; j < 64; ++j) { off[j] = a; a += deg[j]; } off[64] = a; }
    __syncthreads();
    {
      int o = off[l]; const int col = 50 + l;
      for (int i = 0; i < SDIM; ++i)
        if (smask[i*UNITS + col] != 0.f) { ePre[o] = (short)i; ePIdx[o] = (short)l; ++o; }
    }
    if (l == 0) {
      int lam = 0, f = 0, pc = 0;
      for (int p = 0; p < 64; ++p) {
        const int dd = deg[p];
        if (pc == 2 || f == CS || dd > 3*CS - f) { ++lam; f = 0; pc = 0; }
        if (lam > 63) lam = 63;
        pLane[p] = lam; pF0[p] = f; pRole[p] = pc;
        ownP[2*lam + pc] = p;
        const int owner = lam, role = pc; ++pc;
        const int take = dd < (CS - f) ? dd : (CS - f);
        f += take; int rem = dd - take;
        if (rem > 0) {
          splitRole[owner] = role; split2[owner] = (rem > CS) ? 1 : 0;
          ++lam; if (lam > 63) lam = 63; contIdx[lam] = 1; contOwn[lam] = owner; pc = 1;
          const int t2 = rem < CS ? rem : CS; f = t2; rem -= t2;
          if (rem > 0) { ++lam; if (lam > 63) lam = 63; contIdx[lam] = 2; contOwn[lam] = owner; pc = 1; f = rem; }
        }
      }
    }
    __syncthreads();
    int dA = (contIdx[l] == 1) ? contOwn[l] : -1;
    int dB = (contIdx[l] == 2) ? contOwn[l] : -1;
    rcv[l] = 0; __syncthreads();
    if (dA >= 0) rcv[dA] = 1;
    __syncthreads();
    { const unsigned long long rM = __ballot(rcv[l] != 0), dM = __ballot(dA < 0);
      if (dA < 0) dA = kthSetBit(~rM, __popcll(dM & ((1ull << l) - 1ull))); }
    __syncthreads();
    rcv[l] = 0; __syncthreads();
    if (dB >= 0) rcv[dB] = 1;
    __syncthreads();
    { const unsigned long long rM = __ballot(rcv[l] != 0), dM = __ballot(dB < 0);
      if (dB < 0) dB = kthSetBit(~rM, __popcll(dM & ((1ull << l) - 1ull))); }
    __syncthreads();
    int rA = (ownP[2*l]   >= 0) ? canonLane(50 + ownP[2*l])   : -1;
    int rB = (ownP[2*l+1] >= 0) ? canonLane(50 + ownP[2*l+1]) : -1;
    rcv[l] = 0; __syncthreads();
    if (rA >= 0) rcv[rA] = 1;
    __syncthreads();
    const int isRcvA = rcv[l];
    { const unsigned long long rM = __ballot(isRcvA != 0), dM = __ballot(rA < 0);
      if (rA < 0) rA = kthSetBit(~rM, __popcll(dM & ((1ull << l) - 1ull))); }
    __syncthreads();
    rcv[l] = 0; __syncthreads();
    if (rB >= 0) rcv[rB] = 1;
    __syncthreads();
    { const unsigned long long rM = __ballot(rcv[l] != 0), dM = __ballot(rB < 0);
      if (rB < 0) rB = kthSetBit(~rM, __popcll(dM & ((1ull << l) - 1ull))); }
    {
      int* M = meta + l * MSTRIDE;
      M[10] = dA * 4; M[11] = dB * 4;
      const float s1A = (splitRole[l] == 0) ? 1.f : 0.f, s1B = (splitRole[l] == 1) ? 1.f : 0.f;
      M[12] = __float_as_int(s1A); M[13] = __float_as_int(s1B);
      const float s2 = split2[l] ? 1.f : 0.f;
      M[14] = __float_as_int(s1A * s2); M[15] = __float_as_int(s1B * s2);
      M[16] = rA * 4; M[17] = rB * 4;
      M[18] = __float_as_int(isRcvA ? 1.f : 0.f);
      M[19] = __float_as_int(isRcvA ? 0.f : 1.f);
      const int pA = ownP[2*l], pB = ownP[2*l+1];
      M[20] = (pA >= 0) ? 50 + pA : 0;
      M[21] = (pB >= 0) ? 50 + pB : 0;
    }
    for (int t = l; t < CS*64; t += 64) {
      senP4[t] = make_float4(0.f,0.f,0.f,0.f); senP2[t] = make_float2(0.f,0.f); senAd[t] = 0;
    }
    __syncthreads();
    {
      const int E = off[64];
      for (int e = l; e < E; e += 64) {
        const int pre = ePre[e], pj = ePIdx[e];
        const int r  = e - off[pj];
        const int dd = deg[pj], f0 = pF0[pj], role0 = pRole[pj];
        const int take = dd < (CS - f0) ? dd : (CS - f0);
        int lane = pLane[pj], slot, role;
        if (r < take)            { slot = f0 + r;        role = role0; }
        else if (r < take + CS)  { lane += 1; slot = r - take;      role = 0; }
        else                     { lane += 2; slot = r - take - CS; role = 0; }
        if (lane > 63) lane = 63;
        const int col = 50 + pj;
        const int idx = pre * UNITS + col;
        const float sg = ssg[idx];
        const float nsgl = -sg * LOG2E, msl = smu[idx] * sg * LOG2E;
        const float wd = sw[idx], wn = wd * serev[idx];
        const int tt = slot * 64 + lane;
        senP4[tt] = make_float4(nsgl, msl, role ? 0.f : wn, role ? 0.f : wd);
        senP2[tt] = role ? make_float2(wn, wd) : make_float2(0.f, 0.f);
        senAd[tt] = pre * 4;
      }
    }
  }
}

// ---------------------------------------------------------------------------
// Run kernel: one wave per batch element, inline sensory (R6 structure) +
// pairwise-shared rcp, pk-fma with split accumulators, parallel merge rounds.
// All depth-neutral or depth-cheap; no global side-streams.
// ---------------------------------------------------------------------------
__global__ __launch_bounds__(64, 2) void ltc_run(
    const float* __restrict__ obs,     const float* __restrict__ hidden,
    const float* __restrict__ input_w, const float* __restrict__ input_b,
    const float* __restrict__ gleak,   const float* __restrict__ vleak,
    const float* __restrict__ cm,
    const float* __restrict__ q_w1, const float* __restrict__ q_b1,
    const float* __restrict__ q_w2, const float* __restrict__ q_b2,
    const float4* __restrict__ recP4, const float2* __restrict__ recP2,
    const int* __restrict__ recAd,
    const float4* __restrict__ senP4, const float2* __restrict__ senP2,
    const int* __restrict__ senAd,
    const int* __restrict__ meta, float* __restrict__ out, int B)
{
  const int l = threadIdx.x, b = blockIdx.x;
  __shared__ float mirror[256];   // [0..113] units, [128..255] scratch sinks
  char* mbase = (char*)mirror;

  float rNS[CR], rMS[CR]; v2f rWA[CR], rWB[CR]; int rad[CR];
#pragma unroll
  for (int s = 0; s < CR; ++s) {
    const float4 p4 = recP4[s*64 + l]; const float2 p2 = recP2[s*64 + l];
    rNS[s] = p4.x; rMS[s] = p4.y; rWA[s] = (v2f){p4.z, p4.w};
    rWB[s] = (v2f){p2.x, p2.y}; rad[s] = recAd[s*64 + l];
  }
  float sNS[CS], sMS[CS]; v2f sWA[CS], sWB[CS]; int sad[CS];
#pragma unroll
  for (int s = 0; s < CS; ++s) {
    const float4 p4 = senP4[s*64 + l]; const float2 p2 = senP2[s*64 + l];
    sNS[s] = p4.x; sMS[s] = p4.y; sWA[s] = (v2f){p4.z, p4.w};
    sWB[s] = (v2f){p2.x, p2.y}; sad[s] = senAd[s*64 + l];
  }

  const int* M = meta + l * MSTRIDE;
  const int   rPush1 = M[0], rPush2 = M[1];
  const v2f gR1A = {__int_as_float(M[2]), __int_as_float(M[2])};
  const v2f gR1B = {__int_as_float(M[3]), __int_as_float(M[3])};
  const v2f gR2A = {__int_as_float(M[4]), __int_as_float(M[4])};
  const v2f gR2B = {__int_as_float(M[5]), __int_as_float(M[5])};
  const int   rWrA = M[6], rWrB = M[7], rUA = M[8], rUB = M[9];
  const int   sPush1 = M[10], sPush2 = M[11];
  const v2f gS1A = {__int_as_float(M[12]), __int_as_float(M[12])};
  const v2f gS1B = {__int_as_float(M[13]), __int_as_float(M[13])};
  const v2f gS2A = {__int_as_float(M[14]), __int_as_float(M[14])};
  const v2f gS2B = {__int_as_float(M[15]), __int_as_float(M[15])};
  const int   sRtA = M[16], sRtB = M[17];
  const float sRndA = __int_as_float(M[18]), sRndB = __int_as_float(M[19]);
  const int   sUA = M[20], sUB = M[21];

  const float cmA  = cm[rUA]*6.f, glvA  = gleak[rUA]*vleak[rUA], cgA  = cm[rUA]*6.f + gleak[rUA] + EPS;
  const float cmB  = cm[rUB]*6.f, glvB  = gleak[rUB]*vleak[rUB], cgB  = cm[rUB]*6.f + gleak[rUB] + EPS;
  const float cmSA = cm[sUA]*6.f, glvSA = gleak[sUA]*vleak[sUA], cgSA = cm[sUA]*6.f + gleak[sUA] + EPS;
  const float cmSB = cm[sUB]*6.f, glvSB = gleak[sUB]*vleak[sUB], cgSB = cm[sUB]*6.f + gleak[sUB] + EPS;

  const int  iUnit = (l < 50) ? 64 + l : l;
  const int  iWr   = iUnit * 4;
  float vIn = hidden[(size_t)b*UNITS + iUnit];
  float vPA = hidden[(size_t)b*UNITS + rUA];
  float vPB = hidden[(size_t)b*UNITS + rUB];

  mirror[l] = hidden[(size_t)b*UNITS + l];
  if (l < 50) mirror[64 + l] = hidden[(size_t)b*UNITS + 64 + l];

  const float iw = input_w[l], ibv = input_b[l];
  const float* ob = obs + (size_t)b*(TSTEPS*SDIM) + l;
  float xr = ob[0];

  for (int t = 0; t < TSTEPS; ++t) {
    const float xi = xr * iw + ibv;             // lane l holds obs dim l
    if (t + 1 < TSTEPS) xr = ob[(t + 1) * SDIM];

    // ---- sensory -> inter: balanced slots, pairwise rcp, parallel merges ----
    float aI, bI;
    {
      float uu[CS];
#pragma unroll
      for (int s = 0; s < CS; ++s) {
        float z = fmaf(bperm(sad[s], xi), sNS[s], sMS[s]);
        z = fminf(z, 30.f);
        uu[s] = 1.f + __builtin_amdgcn_exp2f(z);
      }
      float sg[CS];
#pragma unroll
      for (int q = 0; q < 4; ++q) {
        const float p = uu[2*q] * uu[2*q+1];
        const float r = __builtin_amdgcn_rcpf(p);
        sg[2*q]   = uu[2*q+1] * r;
        sg[2*q+1] = uu[2*q]   * r;
      }
      sg[8] = __builtin_amdgcn_rcpf(uu[8]);
      v2f a0 = {0.f,0.f}, a1 = {0.f,0.f}, b0 = {0.f,0.f}, b1 = {0.f,0.f};
#pragma unroll
      for (int s = 0; s < CS; ++s) {
        const v2f s2 = {sg[s], sg[s]};
        if (s & 1) { a1 = fma2(sWA[s], s2, a1); b1 = fma2(sWB[s], s2, b1); }
        else       { a0 = fma2(sWA[s], s2, a0); b0 = fma2(sWB[s], s2, b0); }
      }
      v2f cA = a0 + a1, cB = b0 + b1;
      const v2f m1 = {dperm(sPush1, cA.x), dperm(sPush1, cA.y)};
      const v2f m2 = {dperm(sPush2, cA.x), dperm(sPush2, cA.y)};
      v2f tA = fma2(gS1A, m1, cA); tA = fma2(gS2A, m2, tA);
      v2f tB = fma2(gS1B, m1, cB); tB = fma2(gS2B, m2, tB);
      const float rdA = __builtin_amdgcn_rcpf(cgSA + tA.y);
      const float aA = cmSA * rdA, bA = (glvSA + tA.x) * rdA;
      const float rdB = __builtin_amdgcn_rcpf(cgSB + tB.y);
      const float aB = cmSB * rdB, bB = (glvSB + tB.x) * rdB;
      const float ra1 = dperm(sRtA, aA), rb1 = dperm(sRtA, bA);
      const float ra2 = dperm(sRtB, aB), rb2 = dperm(sRtB, bB);
      aI = sRndA*ra1 + sRndB*ra2;
      bI = sRndA*rb1 + sRndB*rb2;
    }

    // ---- 6 ODE unfolds ----
#pragma unroll 1
    for (int u_ = 0; u_ < 6; ++u_) {
      wsync();
      float uu[CR];
#pragma unroll
      for (int s = 0; s < CR; ++s) {
        const float pv = *(const float*)(mbase + rad[s]);
        float z = fmaf(pv, rNS[s], rMS[s]);
        z = fminf(z, 30.f);
        uu[s] = 1.f + __builtin_amdgcn_exp2f(z);
      }
      float sg[CR];
#pragma unroll
      for (int q = 0; q < 6; ++q) {
        const float p = uu[2*q] * uu[2*q+1];
        const float r = __builtin_amdgcn_rcpf(p);
        sg[2*q]   = uu[2*q+1] * r;
        sg[2*q+1] = uu[2*q]   * r;
      }
      sg[12] = __builtin_amdgcn_rcpf(uu[12]);
      v2f a0 = {0.f,0.f}, a1 = {0.f,0.f}, b0 = {0.f,0.f}, b1 = {0.f,0.f};
#pragma unroll
      for (int s = 0; s < CR; ++s) {
        const v2f s2 = {sg[s], sg[s]};
        if (s & 1) { a1 = fma2(rWA[s], s2, a1); b1 = fma2(rWB[s], s2, b1); }
        else       { a0 = fma2(rWA[s], s2, a0); b0 = fma2(rWB[s], s2, b0); }
      }
      v2f aA = a0 + a1, aB = b0 + b1;
      // parallel merge rounds (both push the pre-merge value; proven R6)
      const v2f m1 = {dperm(rPush1, aA.x), dperm(rPush1, aA.y)};
      const v2f m2 = {dperm(rPush2, aA.x), dperm(rPush2, aA.y)};
      v2f tA = fma2(gR1A, m1, aA); tA = fma2(gR2A, m2, tA);
      v2f tB = fma2(gR1B, m1, aB); tB = fma2(gR2B, m2, tB);

      vPA = (fmaf(cmA, vPA, glvA) + tA.x) * __builtin_amdgcn_rcpf(cgA + tA.y);
      vPB = (fmaf(cmB, vPB, glvB) + tB.x) * __builtin_amdgcn_rcpf(cgB + tB.y);
      vIn = fmaf(aI, vIn, bI);
      wsync();
      *(float*)(mbase + rWrA) = vPA;
      *(float*)(mbase + rWrB) = vPB;
      *(float*)(mbase + iWr)  = vIn;
    }
  }
  wsync();

  // ---- outputs: h then Q head ----
  float* __restrict__ outH = out + (size_t)B * ACT;
  outH[(size_t)b*UNITS + l] = mirror[l];
  if (l < 50) outH[(size_t)b*UNITS + 64 + l] = mirror[64 + l];

  const int j2 = (l < 50) ? 64 + l : l;
  float h1 = q_b1[l], h2 = q_b1[j2];
  for (int i = 0; i < UNITS; ++i) {
    const float hv = mirror[i];
    h1 = fmaf(hv, q_w1[i*UNITS + l],  h1);
    h2 = fmaf(hv, q_w1[i*UNITS + j2], h2);
  }
  h1 = fmaxf(h1, 0.f); h2 = fmaxf(h2, 0.f);
  wsync();
  mirror[l] = h1;
  if (l < 50) mirror[64 + l] = h2;
  wsync();
  if (l < ACT) {
    float q = q_b2[l];
    for (int i = 0; i < UNITS; ++i) q = fmaf(mirror[i], q_w2[i*ACT + l], q);
    out[(size_t)b*ACT + l] = q;
  }
}

extern "C" void kernel_launch(void* const* d_in, const int* in_sizes, int n_in,
                              void* d_out, int out_size, void* d_ws, size_t ws_size,
                              hipStream_t stream)
{
  const float* obs           = (const float*)d_in[0];
  const float* hidden        = (const float*)d_in[1];
  const float* input_w       = (const float*)d_in[2];
  const float* input_b       = (const float*)d_in[3];
  const float* sensory_w     = (const float*)d_in[4];
  const float* sensory_mu    = (const float*)d_in[5];
  const float* sensory_sigma = (const float*)d_in[6];
  const float* sensory_erev  = (const float*)d_in[7];
  const float* sensory_mask  = (const float*)d_in[8];
  const float* w             = (const float*)d_in[9];
  const float* mu            = (const float*)d_in[10];
  const float* sigma         = (const float*)d_in[11];
  const float* erev          = (const float*)d_in[12];
  const float* mask          = (const float*)d_in[13];
  const float* gleak         = (const float*)d_in[14];
  const float* vleak         = (const float*)d_in[15];
  const float* cm            = (const float*)d_in[16];
  const float* q_w1          = (const float*)d_in[17];
  const float* q_b1          = (const float*)d_in[18];
  const float* q_w2          = (const float*)d_in[19];
  const float* q_b2          = (const float*)d_in[20];

  char* ws = (char*)d_ws;
  float4* recP4 = (float4*)(ws);            // 13*64*16 = 13312
  float2* recP2 = (float2*)(ws + 13312);    // 13*64*8  = 6656  -> 19968
  int*    recAd = (int*)   (ws + 19968);    // 13*64*4  = 3328  -> 23296
  float4* senP4 = (float4*)(ws + 23296);    // 9*64*16  = 9216  -> 32512
  float2* senP2 = (float2*)(ws + 32512);    // 9*64*8   = 4608  -> 37120
  int*    senAd = (int*)   (ws + 37120);    // 9*64*4   = 2304  -> 39424
  int*    meta  = (int*)   (ws + 39424);    // 64*24*4  = 6144  -> 45568

  build_all<<<2, 64, 0, stream>>>(
      w, mu, sigma, erev, mask,
      sensory_w, sensory_mu, sensory_sigma, sensory_erev, sensory_mask,
      recP4, recP2, recAd, senP4, senP2, senAd, meta);

  const int B = in_sizes[0] / (TSTEPS * SDIM);
  ltc_run<<<B, 64, 0, stream>>>(
      obs, hidden, input_w, input_b, gleak, vleak, cm,
      q_w1, q_b1, q_w2, q_b2,
      recP4, recP2, recAd, senP4, senP2, senAd, meta,
      (float*)d_out, B);
}

// Round 9
// 398.557 us; speedup vs baseline: 1.4262x; 1.0141x over previous
//
#include <hip/hip_runtime.h>

#define UNITS   114
#define SDIM    64
#define ACT     18
#define TSTEPS  64

// Globally-balanced bin-packed slots (placement identical to R4..R7):
//   rec:     E <= 704 edges, max in-degree <= 32. C=13/lane, <=2 posts/lane,
//            <=3 lanes/post. sensory: E == 512, max in-degree <= 20. C=9.
#define CR 13
#define CS 9
#define ER_CAP 704
#define MSTRIDE 24

#define LOG2E 1.4426950408889634f
#define EPS   1e-8f

typedef float v2f __attribute__((ext_vector_type(2)));
__device__ __forceinline__ v2f fma2(v2f a, v2f b, v2f c) {
  return __builtin_elementwise_fma(a, b, c);
}
__device__ __forceinline__ float bperm(int addr, float v) {
  return __int_as_float(__builtin_amdgcn_ds_bpermute(addr, __float_as_int(v)));
}
__device__ __forceinline__ float dperm(int addr, float v) {   // push: lane[addr>>2] <- v
  return __int_as_float(__builtin_amdgcn_ds_permute(addr, __float_as_int(v)));
}
// Wave-internal LDS phase separator (compiler fence + wave barrier, ~0 instr).
__device__ __forceinline__ void wsync() {
  __builtin_amdgcn_fence(__ATOMIC_ACQ_REL, "wavefront");
  __builtin_amdgcn_wave_barrier();
}
__device__ __forceinline__ int canonLane(int u) { return (u >= 64) ? (u - 64) : u; }

// k-th set bit of a 64-bit mask (k 0-based).
__device__ __forceinline__ int kthSetBit(unsigned long long m, int k) {
  int pos = 0;
#pragma unroll
  for (int ww = 32; ww >= 1; ww >>= 1) {
    const unsigned long long lowMask = ((1ull << ww) - 1ull);
    const int c = __popcll(m & lowMask);
    if (k >= c) { k -= c; m >>= ww; pos += ww; }
  }
  return pos;
}

// ---------------------------------------------------------------------------
// Build: 2 blocks (rec / sensory). R8: global-scan loops are 16-wide
// chunk-unrolled (loads staged to registers first -> all in flight), the
// R2-proven pattern. Placement logic and outputs identical to R5..R7.
// ---------------------------------------------------------------------------
__global__ __launch_bounds__(64) void build_all(
    const float* __restrict__ w,  const float* __restrict__ mu,
    const float* __restrict__ sigma, const float* __restrict__ erev,
    const float* __restrict__ mask,
    const float* __restrict__ sw, const float* __restrict__ smu,
    const float* __restrict__ ssg, const float* __restrict__ serev,
    const float* __restrict__ smask,
    float4* __restrict__ recP4, float2* __restrict__ recP2, int* __restrict__ recAd,
    float4* __restrict__ senP4, float2* __restrict__ senP2, int* __restrict__ senAd,
    int* __restrict__ meta)
{
  const int l = threadIdx.x;
  __shared__ short ePre[ER_CAP], ePIdx[ER_CAP];
  __shared__ int deg[64], off[65];
  __shared__ int pLane[64], pF0[64], pRole[64];
  __shared__ int contIdx[64], contOwn[64], splitRole[64], split2[64], ownP[128];
  __shared__ int rcv[64];

  contIdx[l] = 0; contOwn[l] = 0; splitRole[l] = -1; split2[l] = 0;
  ownP[2*l] = -1; ownP[2*l+1] = -1;
  pLane[l] = 0; pF0[l] = 0; pRole[l] = 0;

  if (blockIdx.x == 0) {
    // =========== recurrent (posts 0..49, pres 18..113) ===========
    int d = 0;
    if (l < 50) {
      for (int base = 18; base < 114; base += 16) {
        float mv[16];
#pragma unroll
        for (int q = 0; q < 16; ++q) mv[q] = mask[(base + q)*UNITS + l];
#pragma unroll
        for (int q = 0; q < 16; ++q) d += (mv[q] != 0.f) ? 1 : 0;
      }
    }
    deg[l] = (l < 50) ? d : 0;
    __syncthreads();
    if (l == 0) { int a = 0; for (int j = 0; j < 64; ++j) { off[j] = a; a += deg[j]; } off[64] = a; }
    __syncthreads();
    if (l < 50) {
      int o = off[l];
      for (int base = 18; base < 114; base += 16) {
        float mv[16];
#pragma unroll
        for (int q = 0; q < 16; ++q) mv[q] = mask[(base + q)*UNITS + l];
#pragma unroll
        for (int q = 0; q < 16; ++q)
          if (mv[q] != 0.f) { ePre[o] = (short)(base + q); ePIdx[o] = (short)l; ++o; }
      }
    }
    if (l == 0) {
      int lam = 0, f = 0, pc = 0;
      for (int p = 0; p < 50; ++p) {
        const int dd = deg[p];
        if (pc == 2 || f == CR || dd > 3*CR - f) { ++lam; f = 0; pc = 0; }
        if (lam > 63) lam = 63;
        pLane[p] = lam; pF0[p] = f; pRole[p] = pc;
        ownP[2*lam + pc] = p;
        const int owner = lam, role = pc; ++pc;
        const int take = dd < (CR - f) ? dd : (CR - f);
        f += take; int rem = dd - take;
        if (rem > 0) {
          splitRole[owner] = role; split2[owner] = (rem > CR) ? 1 : 0;
          ++lam; if (lam > 63) lam = 63; contIdx[lam] = 1; contOwn[lam] = owner; pc = 1;
          const int t2 = rem < CR ? rem : CR; f = t2; rem -= t2;
          if (rem > 0) { ++lam; if (lam > 63) lam = 63; contIdx[lam] = 2; contOwn[lam] = owner; pc = 1; f = rem; }
        }
      }
    }
    __syncthreads();
    int dA = (contIdx[l] == 1) ? contOwn[l] : -1;
    int dB = (contIdx[l] == 2) ? contOwn[l] : -1;
    rcv[l] = 0; __syncthreads();
    if (dA >= 0) rcv[dA] = 1;
    __syncthreads();
    { const unsigned long long rM = __ballot(rcv[l] != 0), dM = __ballot(dA < 0);
      if (dA < 0) dA = kthSetBit(~rM, __popcll(dM & ((1ull << l) - 1ull))); }
    __syncthreads();
    rcv[l] = 0; __syncthreads();
    if (dB >= 0) rcv[dB] = 1;
    __syncthreads();
    { const unsigned long long rM = __ballot(rcv[l] != 0), dM = __ballot(dB < 0);
      if (dB < 0) dB = kthSetBit(~rM, __popcll(dM & ((1ull << l) - 1ull))); }
    {
      int* M = meta + l * MSTRIDE;
      M[0] = dA * 4; M[1] = dB * 4;
      const float s1A = (splitRole[l] == 0) ? 1.f : 0.f, s1B = (splitRole[l] == 1) ? 1.f : 0.f;
      M[2] = __float_as_int(s1A); M[3] = __float_as_int(s1B);
      const float s2 = split2[l] ? 1.f : 0.f;
      M[4] = __float_as_int(s1A * s2); M[5] = __float_as_int(s1B * s2);
      const int uA = ownP[2*l], uB = ownP[2*l+1];
      M[6] = ((uA >= 0) ? uA : 128 + l) * 4;
      M[7] = ((uB >= 0) ? uB : 192 + l) * 4;
      M[8] = (uA >= 0) ? uA : 0;
      M[9] = (uB >= 0) ? uB : 0;
    }
    for (int t = l; t < CR*64; t += 64) {
      recP4[t] = make_float4(0.f,0.f,0.f,0.f); recP2[t] = make_float2(0.f,0.f); recAd[t] = 0;
    }
    __syncthreads();
    {
      const int E = off[64];
      for (int e = l; e < E; e += 64) {
        const int pre = ePre[e], pj = ePIdx[e];
        const int r  = e - off[pj];
        const int dd = deg[pj], f0 = pF0[pj], role0 = pRole[pj];
        const int take = dd < (CR - f0) ? dd : (CR - f0);
        int lane = pLane[pj], slot, role;
        if (r < take)            { slot = f0 + r;        role = role0; }
        else if (r < take + CR)  { lane += 1; slot = r - take;      role = 0; }
        else                     { lane += 2; slot = r - take - CR; role = 0; }
        if (lane > 63) lane = 63;
        const int idx = pre * UNITS + pj;
        const float sg = sigma[idx];
        const float nsgl = -sg * LOG2E, msl = mu[idx] * sg * LOG2E;
        const float wd = w[idx], wn = wd * erev[idx];
        const int tt = slot * 64 + lane;
        recP4[tt] = make_float4(nsgl, msl, role ? 0.f : wn, role ? 0.f : wd);
        recP2[tt] = role ? make_float2(wn, wd) : make_float2(0.f, 0.f);
        recAd[tt] = pre * 4;
      }
    }
  } else {
    // =========== sensory (posts 0..63 -> units 50..113, pres 0..63) ===========
    int d = 0;
    {
      const int col = 50 + l;
      for (int base = 0; base < 64; base += 16) {
        float mv[16];
#pragma unroll
        for (int q = 0; q < 16; ++q) mv[q] = smask[(base + q)*UNITS + col];
#pragma unroll
        for (int q = 0; q < 16; ++q) d += (mv[q] != 0.f) ? 1 : 0;
      }
    }
    deg[l] = d;
    __syncthreads();
    if (l == 0) { int a = 0; for (int j = 0; j < 64; ++j) { off[j] = a; a += deg[j]; } off[64] = a; }
    __syncthreads();
    {
      int o = off[l]; const int col = 50 + l;
      for (int base = 0; base < 64; base += 16) {
        float mv[16];
#pragma unroll
        for (int q = 0; q < 16; ++q) mv[q] = smask[(base + q)*UNITS + col];
#pragma unroll
        for (int q = 0; q < 16; ++q)
          if (mv[q] != 0.f) { ePre[o] = (short)(base + q); ePIdx[o] = (short)l; ++o; }
      }
    }
    if (l == 0) {
      int lam = 0, f = 0, pc = 0;
      for (int p = 0; p < 64; ++p) {
        const int dd = deg[p];
        if (pc == 2 || f == CS || dd > 3*CS - f) { ++lam; f = 0; pc = 0; }
        if (lam > 63) lam = 63;
        pLane[p] = lam; pF0[p] = f; pRole[p] = pc;
        ownP[2*lam + pc] = p;
        const int owner = lam, role = pc; ++pc;
        const int take = dd < (CS - f) ? dd : (CS - f);
        f += take; int rem = dd - take;
        if (rem > 0) {
          splitRole[owner] = role; split2[owner] = (rem > CS) ? 1 : 0;
          ++lam; if (lam > 63) lam = 63; contIdx[lam] = 1; contOwn[lam] = owner; pc = 1;
          const int t2 = rem < CS ? rem : CS; f = t2; rem -= t2;
          if (rem > 0) { ++lam; if (lam > 63) lam = 63; contIdx[lam] = 2; contOwn[lam] = owner; pc = 1; f = rem; }
        }
      }
    }
    __syncthreads();
    int dA = (contIdx[l] == 1) ? contOwn[l] : -1;
    int dB = (contIdx[l] == 2) ? contOwn[l] : -1;
    rcv[l] = 0; __syncthreads();
    if (dA >= 0) rcv[dA] = 1;
    __syncthreads();
    { const unsigned long long rM = __ballot(rcv[l] != 0), dM = __ballot(dA < 0);
      if (dA < 0) dA = kthSetBit(~rM, __popcll(dM & ((1ull << l) - 1ull))); }
    __syncthreads();
    rcv[l] = 0; __syncthreads();
    if (dB >= 0) rcv[dB] = 1;
    __syncthreads();
    { const unsigned long long rM = __ballot(rcv[l] != 0), dM = __ballot(dB < 0);
      if (dB < 0) dB = kthSetBit(~rM, __popcll(dM & ((1ull << l) - 1ull))); }
    __syncthreads();
    int rA = (ownP[2*l]   >= 0) ? canonLane(50 + ownP[2*l])   : -1;
    int rB = (ownP[2*l+1] >= 0) ? canonLane(50 + ownP[2*l+1]) : -1;
    rcv[l] = 0; __syncthreads();
    if (rA >= 0) rcv[rA] = 1;
    __syncthreads();
    const int isRcvA = rcv[l];
    { const unsigned long long rM = __ballot(isRcvA != 0), dM = __ballot(rA < 0);
      if (rA < 0) rA = kthSetBit(~rM, __popcll(dM & ((1ull << l) - 1ull))); }
    __syncthreads();
    rcv[l] = 0; __syncthreads();
    if (rB >= 0) rcv[rB] = 1;
    __syncthreads();
    { const unsigned long long rM = __ballot(rcv[l] != 0), dM = __ballot(rB < 0);
      if (rB < 0) rB = kthSetBit(~rM, __popcll(dM & ((1ull << l) - 1ull))); }
    {
      int* M = meta + l * MSTRIDE;
      M[10] = dA * 4; M[11] = dB * 4;
      const float s1A = (splitRole[l] == 0) ? 1.f : 0.f, s1B = (splitRole[l] == 1) ? 1.f : 0.f;
      M[12] = __float_as_int(s1A); M[13] = __float_as_int(s1B);
      const float s2 = split2[l] ? 1.f : 0.f;
      M[14] = __float_as_int(s1A * s2); M[15] = __float_as_int(s1B * s2);
      M[16] = rA * 4; M[17] = rB * 4;
      M[18] = __float_as_int(isRcvA ? 1.f : 0.f);
      M[19] = __float_as_int(isRcvA ? 0.f : 1.f);
      const int pA = ownP[2*l], pB = ownP[2*l+1];
      M[20] = (pA >= 0) ? 50 + pA : 0;
      M[21] = (pB >= 0) ? 50 + pB : 0;
    }
    for (int t = l; t < CS*64; t += 64) {
      senP4[t] = make_float4(0.f,0.f,0.f,0.f); senP2[t] = make_float2(0.f,0.f); senAd[t] = 0;
    }
    __syncthreads();
    {
      const int E = off[64];
      for (int e = l; e < E; e += 64) {
        const int pre = ePre[e], pj = ePIdx[e];
        const int r  = e - off[pj];
        const int dd = deg[pj], f0 = pF0[pj], role0 = pRole[pj];
        const int take = dd < (CS - f0) ? dd : (CS - f0);
        int lane = pLane[pj], slot, role;
        if (r < take)            { slot = f0 + r;        role = role0; }
        else if (r < take + CS)  { lane += 1; slot = r - take;      role = 0; }
        else                     { lane += 2; slot = r - take - CS; role = 0; }
        if (lane > 63) lane = 63;
        const int col = 50 + pj;
        const int idx = pre * UNITS + col;
        const float sg = ssg[idx];
        const float nsgl = -sg * LOG2E, msl = smu[idx] * sg * LOG2E;
        const float wd = sw[idx], wn = wd * serev[idx];
        const int tt = slot * 64 + lane;
        senP4[tt] = make_float4(nsgl, msl, role ? 0.f : wn, role ? 0.f : wd);
        senP2[tt] = role ? make_float2(wn, wd) : make_float2(0.f, 0.f);
        senAd[tt] = pre * 4;
      }
    }
  }
}

// ---------------------------------------------------------------------------
// Run kernel: UNCHANGED from R7 (proven 311 us / absmax 0.00195).
// One wave per batch element, inline sensory, pairwise-shared rcp, pk-fma
// split accumulators, parallel dperm merge rounds, LDS mirror + wsync.
// ---------------------------------------------------------------------------
__global__ __launch_bounds__(64, 2) void ltc_run(
    const float* __restrict__ obs,     const float* __restrict__ hidden,
    const float* __restrict__ input_w, const float* __restrict__ input_b,
    const float* __restrict__ gleak,   const float* __restrict__ vleak,
    const float* __restrict__ cm,
    const float* __restrict__ q_w1, const float* __restrict__ q_b1,
    const float* __restrict__ q_w2, const float* __restrict__ q_b2,
    const float4* __restrict__ recP4, const float2* __restrict__ recP2,
    const int* __restrict__ recAd,
    const float4* __restrict__ senP4, const float2* __restrict__ senP2,
    const int* __restrict__ senAd,
    const int* __restrict__ meta, float* __restrict__ out, int B)
{
  const int l = threadIdx.x, b = blockIdx.x;
  __shared__ float mirror[256];   // [0..113] units, [128..255] scratch sinks
  char* mbase = (char*)mirror;

  float rNS[CR], rMS[CR]; v2f rWA[CR], rWB[CR]; int rad[CR];
#pragma unroll
  for (int s = 0; s < CR; ++s) {
    const float4 p4 = recP4[s*64 + l]; const float2 p2 = recP2[s*64 + l];
    rNS[s] = p4.x; rMS[s] = p4.y; rWA[s] = (v2f){p4.z, p4.w};
    rWB[s] = (v2f){p2.x, p2.y}; rad[s] = recAd[s*64 + l];
  }
  float sNS[CS], sMS[CS]; v2f sWA[CS], sWB[CS]; int sad[CS];
#pragma unroll
  for (int s = 0; s < CS; ++s) {
    const float4 p4 = senP4[s*64 + l]; const float2 p2 = senP2[s*64 + l];
    sNS[s] = p4.x; sMS[s] = p4.y; sWA[s] = (v2f){p4.z, p4.w};
    sWB[s] = (v2f){p2.x, p2.y}; sad[s] = senAd[s*64 + l];
  }

  const int* M = meta + l * MSTRIDE;
  const int   rPush1 = M[0], rPush2 = M[1];
  const v2f gR1A = {__int_as_float(M[2]), __int_as_float(M[2])};
  const v2f gR1B = {__int_as_float(M[3]), __int_as_float(M[3])};
  const v2f gR2A = {__int_as_float(M[4]), __int_as_float(M[4])};
  const v2f gR2B = {__int_as_float(M[5]), __int_as_float(M[5])};
  const int   rWrA = M[6], rWrB = M[7], rUA = M[8], rUB = M[9];
  const int   sPush1 = M[10], sPush2 = M[11];
  const v2f gS1A = {__int_as_float(M[12]), __int_as_float(M[12])};
  const v2f gS1B = {__int_as_float(M[13]), __int_as_float(M[13])};
  const v2f gS2A = {__int_as_float(M[14]), __int_as_float(M[14])};
  const v2f gS2B = {__int_as_float(M[15]), __int_as_float(M[15])};
  const int   sRtA = M[16], sRtB = M[17];
  const float sRndA = __int_as_float(M[18]), sRndB = __int_as_float(M[19]);
  const int   sUA = M[20], sUB = M[21];

  const float cmA  = cm[rUA]*6.f, glvA  = gleak[rUA]*vleak[rUA], cgA  = cm[rUA]*6.f + gleak[rUA] + EPS;
  const float cmB  = cm[rUB]*6.f, glvB  = gleak[rUB]*vleak[rUB], cgB  = cm[rUB]*6.f + gleak[rUB] + EPS;
  const float cmSA = cm[sUA]*6.f, glvSA = gleak[sUA]*vleak[sUA], cgSA = cm[sUA]*6.f + gleak[sUA] + EPS;
  const float cmSB = cm[sUB]*6.f, glvSB = gleak[sUB]*vleak[sUB], cgSB = cm[sUB]*6.f + gleak[sUB] + EPS;

  const int  iUnit = (l < 50) ? 64 + l : l;
  const int  iWr   = iUnit * 4;
  float vIn = hidden[(size_t)b*UNITS + iUnit];
  float vPA = hidden[(size_t)b*UNITS + rUA];
  float vPB = hidden[(size_t)b*UNITS + rUB];

  mirror[l] = hidden[(size_t)b*UNITS + l];
  if (l < 50) mirror[64 + l] = hidden[(size_t)b*UNITS + 64 + l];

  const float iw = input_w[l], ibv = input_b[l];
  const float* ob = obs + (size_t)b*(TSTEPS*SDIM) + l;
  float xr = ob[0];

  for (int t = 0; t < TSTEPS; ++t) {
    const float xi = xr * iw + ibv;             // lane l holds obs dim l
    if (t + 1 < TSTEPS) xr = ob[(t + 1) * SDIM];

    // ---- sensory -> inter: balanced slots, pairwise rcp, parallel merges ----
    float aI, bI;
    {
      float uu[CS];
#pragma unroll
      for (int s = 0; s < CS; ++s) {
        float z = fmaf(bperm(sad[s], xi), sNS[s], sMS[s]);
        z = fminf(z, 30.f);
        uu[s] = 1.f + __builtin_amdgcn_exp2f(z);
      }
      float sg[CS];
#pragma unroll
      for (int q = 0; q < 4; ++q) {
        const float p = uu[2*q] * uu[2*q+1];
        const float r = __builtin_amdgcn_rcpf(p);
        sg[2*q]   = uu[2*q+1] * r;
        sg[2*q+1] = uu[2*q]   * r;
      }
      sg[8] = __builtin_amdgcn_rcpf(uu[8]);
      v2f a0 = {0.f,0.f}, a1 = {0.f,0.f}, b0 = {0.f,0.f}, b1 = {0.f,0.f};
#pragma unroll
      for (int s = 0; s < CS; ++s) {
        const v2f s2 = {sg[s], sg[s]};
        if (s & 1) { a1 = fma2(sWA[s], s2, a1); b1 = fma2(sWB[s], s2, b1); }
        else       { a0 = fma2(sWA[s], s2, a0); b0 = fma2(sWB[s], s2, b0); }
      }
      v2f cA = a0 + a1, cB = b0 + b1;
      const v2f m1 = {dperm(sPush1, cA.x), dperm(sPush1, cA.y)};
      const v2f m2 = {dperm(sPush2, cA.x), dperm(sPush2, cA.y)};
      v2f tA = fma2(gS1A, m1, cA); tA = fma2(gS2A, m2, tA);
      v2f tB = fma2(gS1B, m1, cB); tB = fma2(gS2B, m2, tB);
      const float rdA = __builtin_amdgcn_rcpf(cgSA + tA.y);
      const float aA = cmSA * rdA, bA = (glvSA + tA.x) * rdA;
      const float rdB = __builtin_amdgcn_rcpf(cgSB + tB.y);
      const float aB = cmSB * rdB, bB = (glvSB + tB.x) * rdB;
      const float ra1 = dperm(sRtA, aA), rb1 = dperm(sRtA, bA);
      const float ra2 = dperm(sRtB, aB), rb2 = dperm(sRtB, bB);
      aI = sRndA*ra1 + sRndB*ra2;
      bI = sRndA*rb1 + sRndB*rb2;
    }

    // ---- 6 ODE unfolds ----
#pragma unroll 1
    for (int u_ = 0; u_ < 6; ++u_) {
      wsync();
      float uu[CR];
#pragma unroll
      for (int s = 0; s < CR; ++s) {
        const float pv = *(const float*)(mbase + rad[s]);
        float z = fmaf(pv, rNS[s], rMS[s]);
        z = fminf(z, 30.f);
        uu[s] = 1.f + __builtin_amdgcn_exp2f(z);
      }
      float sg[CR];
#pragma unroll
      for (int q = 0; q < 6; ++q) {
        const float p = uu[2*q] * uu[2*q+1];
        const float r = __builtin_amdgcn_rcpf(p);
        sg[2*q]   = uu[2*q+1] * r;
        sg[2*q+1] = uu[2*q]   * r;
      }
      sg[12] = __builtin_amdgcn_rcpf(uu[12]);
      v2f a0 = {0.f,0.f}, a1 = {0.f,0.f}, b0 = {0.f,0.f}, b1 = {0.f,0.f};
#pragma unroll
      for (int s = 0; s < CR; ++s) {
        const v2f s2 = {sg[s], sg[s]};
        if (s & 1) { a1 = fma2(rWA[s], s2, a1); b1 = fma2(rWB[s], s2, b1); }
        else       { a0 = fma2(rWA[s], s2, a0); b0 = fma2(rWB[s], s2, b0); }
      }
      v2f aA = a0 + a1, aB = b0 + b1;
      // parallel merge rounds (both push the pre-merge value; proven R6/R7)
      const v2f m1 = {dperm(rPush1, aA.x), dperm(rPush1, aA.y)};
      const v2f m2 = {dperm(rPush2, aA.x), dperm(rPush2, aA.y)};
      v2f tA = fma2(gR1A, m1, aA); tA = fma2(gR2A, m2, tA);
      v2f tB = fma2(gR1B, m1, aB); tB = fma2(gR2B, m2, tB);

      vPA = (fmaf(cmA, vPA, glvA) + tA.x) * __builtin_amdgcn_rcpf(cgA + tA.y);
      vPB = (fmaf(cmB, vPB, glvB) + tB.x) * __builtin_amdgcn_rcpf(cgB + tB.y);
      vIn = fmaf(aI, vIn, bI);
      wsync();
      *(float*)(mbase + rWrA) = vPA;
      *(float*)(mbase + rWrB) = vPB;
      *(float*)(mbase + iWr)  = vIn;
    }
  }
  wsync();

  // ---- outputs: h then Q head ----
  float* __restrict__ outH = out + (size_t)B * ACT;
  outH[(size_t)b*UNITS + l] = mirror[l];
  if (l < 50) outH[(size_t)b*UNITS + 64 + l] = mirror[64 + l];

  const int j2 = (l < 50) ? 64 + l : l;
  float h1 = q_b1[l], h2 = q_b1[j2];
  for (int i = 0; i < UNITS; ++i) {
    const float hv = mirror[i];
    h1 = fmaf(hv, q_w1[i*UNITS + l],  h1);
    h2 = fmaf(hv, q_w1[i*UNITS + j2], h2);
  }
  h1 = fmaxf(h1, 0.f); h2 = fmaxf(h2, 0.f);
  wsync();
  mirror[l] = h1;
  if (l < 50) mirror[64 + l] = h2;
  wsync();
  if (l < ACT) {
    float q = q_b2[l];
    for (int i = 0; i < UNITS; ++i) q = fmaf(mirror[i], q_w2[i*ACT + l], q);
    out[(size_t)b*ACT + l] = q;
  }
}

extern "C" void kernel_launch(void* const* d_in, const int* in_sizes, int n_in,
                              void* d_out, int out_size, void* d_ws, size_t ws_size,
                              hipStream_t stream)
{
  const float* obs           = (const float*)d_in[0];
  const float* hidden        = (const float*)d_in[1];
  const float* input_w       = (const float*)d_in[2];
  const float* input_b       = (const float*)d_in[3];
  const float* sensory_w     = (const float*)d_in[4];
  const float* sensory_mu    = (const float*)d_in[5];
  const float* sensory_sigma = (const float*)d_in[6];
  const float* sensory_erev  = (const float*)d_in[7];
  const float* sensory_mask  = (const float*)d_in[8];
  const float* w             = (const float*)d_in[9];
  const float* mu            = (const float*)d_in[10];
  const float* sigma         = (const float*)d_in[11];
  const float* erev          = (const float*)d_in[12];
  const float* mask          = (const float*)d_in[13];
  const float* gleak         = (const float*)d_in[14];
  const float* vleak         = (const float*)d_in[15];
  const float* cm            = (const float*)d_in[16];
  const float* q_w1          = (const float*)d_in[17];
  const float* q_b1          = (const float*)d_in[18];
  const float* q_w2          = (const float*)d_in[19];
  const float* q_b2          = (const float*)d_in[20];

  char* ws = (char*)d_ws;
  float4* recP4 = (float4*)(ws);            // 13*64*16 = 13312
  float2* recP2 = (float2*)(ws + 13312);    // 13*64*8  = 6656  -> 19968
  int*    recAd = (int*)   (ws + 19968);    // 13*64*4  = 3328  -> 23296
  float4* senP4 = (float4*)(ws + 23296);    // 9*64*16  = 9216  -> 32512
  float2* senP2 = (float2*)(ws + 32512);    // 9*64*8   = 4608  -> 37120
  int*    senAd = (int*)   (ws + 37120);    // 9*64*4   = 2304  -> 39424
  int*    meta  = (int*)   (ws + 39424);    // 64*24*4  = 6144  -> 45568

  build_all<<<2, 64, 0, stream>>>(
      w, mu, sigma, erev, mask,
      sensory_w, sensory_mu, sensory_sigma, sensory_erev, sensory_mask,
      recP4, recP2, recAd, senP4, senP2, senAd, meta);

  const int B = in_sizes[0] / (TSTEPS * SDIM);
  ltc_run<<<B, 64, 0, stream>>>(
      obs, hidden, input_w, input_b, gleak, vleak, cm,
      q_w1, q_b1, q_w2, q_b2,
      recP4, recP2, recAd, senP4, senP2, senAd, meta,
      (float*)d_out, B);
}

// Round 10
// 382.606 us; speedup vs baseline: 1.4856x; 1.0417x over previous
//
#include <hip/hip_runtime.h>

#define UNITS   114
#define SDIM    64
#define ACT     18
#define TSTEPS  64

// Globally-balanced bin-packed slots (placement identical to R4..R8):
//   rec:     E <= 704 edges, max in-degree <= 32. C=13/lane, <=2 posts/lane,
//            <=3 lanes/post. sensory: E == 512, max in-degree <= 20. C=9.
#define CR 13
#define CS 9
#define ER_CAP 704
#define MSTRIDE 24

#define LOG2E 1.4426950408889634f
#define EPS   1e-8f

typedef float v2f __attribute__((ext_vector_type(2)));
__device__ __forceinline__ v2f fma2(v2f a, v2f b, v2f c) {
  return __builtin_elementwise_fma(a, b, c);
}
__device__ __forceinline__ float bperm(int addr, float v) {
  return __int_as_float(__builtin_amdgcn_ds_bpermute(addr, __float_as_int(v)));
}
__device__ __forceinline__ float dperm(int addr, float v) {   // push: lane[addr>>2] <- v
  return __int_as_float(__builtin_amdgcn_ds_permute(addr, __float_as_int(v)));
}
// Wave-internal LDS phase separator (compiler fence + wave barrier, ~0 instr).
__device__ __forceinline__ void wsync() {
  __builtin_amdgcn_fence(__ATOMIC_ACQ_REL, "wavefront");
  __builtin_amdgcn_wave_barrier();
}
__device__ __forceinline__ int canonLane(int u) { return (u >= 64) ? (u - 64) : u; }

// k-th set bit of a 64-bit mask (k 0-based).
__device__ __forceinline__ int kthSetBit(unsigned long long m, int k) {
  int pos = 0;
#pragma unroll
  for (int ww = 32; ww >= 1; ww >>= 1) {
    const unsigned long long lowMask = ((1ull << ww) - 1ull);
    const int c = __popcll(m & lowMask);
    if (k >= c) { k -= c; m >>= ww; pos += ww; }
  }
  return pos;
}

// ---------------------------------------------------------------------------
// Build (unchanged from R8, proven): 2 blocks, chunk-unrolled scans.
// ---------------------------------------------------------------------------
__global__ __launch_bounds__(64) void build_all(
    const float* __restrict__ w,  const float* __restrict__ mu,
    const float* __restrict__ sigma, const float* __restrict__ erev,
    const float* __restrict__ mask,
    const float* __restrict__ sw, const float* __restrict__ smu,
    const float* __restrict__ ssg, const float* __restrict__ serev,
    const float* __restrict__ smask,
    float4* __restrict__ recP4, float2* __restrict__ recP2, int* __restrict__ recAd,
    float4* __restrict__ senP4, float2* __restrict__ senP2, int* __restrict__ senAd,
    int* __restrict__ meta)
{
  const int l = threadIdx.x;
  __shared__ short ePre[ER_CAP], ePIdx[ER_CAP];
  __shared__ int deg[64], off[65];
  __shared__ int pLane[64], pF0[64], pRole[64];
  __shared__ int contIdx[64], contOwn[64], splitRole[64], split2[64], ownP[128];
  __shared__ int rcv[64];

  contIdx[l] = 0; contOwn[l] = 0; splitRole[l] = -1; split2[l] = 0;
  ownP[2*l] = -1; ownP[2*l+1] = -1;
  pLane[l] = 0; pF0[l] = 0; pRole[l] = 0;

  if (blockIdx.x == 0) {
    int d = 0;
    if (l < 50) {
      for (int base = 18; base < 114; base += 16) {
        float mv[16];
#pragma unroll
        for (int q = 0; q < 16; ++q) mv[q] = mask[(base + q)*UNITS + l];
#pragma unroll
        for (int q = 0; q < 16; ++q) d += (mv[q] != 0.f) ? 1 : 0;
      }
    }
    deg[l] = (l < 50) ? d : 0;
    __syncthreads();
    if (l == 0) { int a = 0; for (int j = 0; j < 64; ++j) { off[j] = a; a += deg[j]; } off[64] = a; }
    __syncthreads();
    if (l < 50) {
      int o = off[l];
      for (int base = 18; base < 114; base += 16) {
        float mv[16];
#pragma unroll
        for (int q = 0; q < 16; ++q) mv[q] = mask[(base + q)*UNITS + l];
#pragma unroll
        for (int q = 0; q < 16; ++q)
          if (mv[q] != 0.f) { ePre[o] = (short)(base + q); ePIdx[o] = (short)l; ++o; }
      }
    }
    if (l == 0) {
      int lam = 0, f = 0, pc = 0;
      for (int p = 0; p < 50; ++p) {
        const int dd = deg[p];
        if (pc == 2 || f == CR || dd > 3*CR - f) { ++lam; f = 0; pc = 0; }
        if (lam > 63) lam = 63;
        pLane[p] = lam; pF0[p] = f; pRole[p] = pc;
        ownP[2*lam + pc] = p;
        const int owner = lam, role = pc; ++pc;
        const int take = dd < (CR - f) ? dd : (CR - f);
        f += take; int rem = dd - take;
        if (rem > 0) {
          splitRole[owner] = role; split2[owner] = (rem > CR) ? 1 : 0;
          ++lam; if (lam > 63) lam = 63; contIdx[lam] = 1; contOwn[lam] = owner; pc = 1;
          const int t2 = rem < CR ? rem : CR; f = t2; rem -= t2;
          if (rem > 0) { ++lam; if (lam > 63) lam = 63; contIdx[lam] = 2; contOwn[lam] = owner; pc = 1; f = rem; }
        }
      }
    }
    __syncthreads();
    int dA = (contIdx[l] == 1) ? contOwn[l] : -1;
    int dB = (contIdx[l] == 2) ? contOwn[l] : -1;
    rcv[l] = 0; __syncthreads();
    if (dA >= 0) rcv[dA] = 1;
    __syncthreads();
    { const unsigned long long rM = __ballot(rcv[l] != 0), dM = __ballot(dA < 0);
      if (dA < 0) dA = kthSetBit(~rM, __popcll(dM & ((1ull << l) - 1ull))); }
    __syncthreads();
    rcv[l] = 0; __syncthreads();
    if (dB >= 0) rcv[dB] = 1;
    __syncthreads();
    { const unsigned long long rM = __ballot(rcv[l] != 0), dM = __ballot(dB < 0);
      if (dB < 0) dB = kthSetBit(~rM, __popcll(dM & ((1ull << l) - 1ull))); }
    {
      int* M = meta + l * MSTRIDE;
      M[0] = dA * 4; M[1] = dB * 4;
      const float s1A = (splitRole[l] == 0) ? 1.f : 0.f, s1B = (splitRole[l] == 1) ? 1.f : 0.f;
      M[2] = __float_as_int(s1A); M[3] = __float_as_int(s1B);
      const float s2 = split2[l] ? 1.f : 0.f;
      M[4] = __float_as_int(s1A * s2); M[5] = __float_as_int(s1B * s2);
      const int uA = ownP[2*l], uB = ownP[2*l+1];
      M[6] = ((uA >= 0) ? uA : 128 + l) * 4;
      M[7] = ((uB >= 0) ? uB : 192 + l) * 4;
      M[8] = (uA >= 0) ? uA : 0;
      M[9] = (uB >= 0) ? uB : 0;
    }
    for (int t = l; t < CR*64; t += 64) {
      recP4[t] = make_float4(0.f,0.f,0.f,0.f); recP2[t] = make_float2(0.f,0.f); recAd[t] = 0;
    }
    __syncthreads();
    {
      const int E = off[64];
      for (int e = l; e < E; e += 64) {
        const int pre = ePre[e], pj = ePIdx[e];
        const int r  = e - off[pj];
        const int dd = deg[pj], f0 = pF0[pj], role0 = pRole[pj];
        const int take = dd < (CR - f0) ? dd : (CR - f0);
        int lane = pLane[pj], slot, role;
        if (r < take)            { slot = f0 + r;        role = role0; }
        else if (r < take + CR)  { lane += 1; slot = r - take;      role = 0; }
        else                     { lane += 2; slot = r - take - CR; role = 0; }
        if (lane > 63) lane = 63;
        const int idx = pre * UNITS + pj;
        const float sg = sigma[idx];
        const float nsgl = -sg * LOG2E, msl = mu[idx] * sg * LOG2E;
        const float wd = w[idx], wn = wd * erev[idx];
        const int tt = slot * 64 + lane;
        recP4[tt] = make_float4(nsgl, msl, role ? 0.f : wn, role ? 0.f : wd);
        recP2[tt] = role ? make_float2(wn, wd) : make_float2(0.f, 0.f);
        recAd[tt] = pre * 4;
      }
    }
  } else {
    int d = 0;
    {
      const int col = 50 + l;
      for (int base = 0; base < 64; base += 16) {
        float mv[16];
#pragma unroll
        for (int q = 0; q < 16; ++q) mv[q] = smask[(base + q)*UNITS + col];
#pragma unroll
        for (int q = 0; q < 16; ++q) d += (mv[q] != 0.f) ? 1 : 0;
      }
    }
    deg[l] = d;
    __syncthreads();
    if (l == 0) { int a = 0; for (int j = 0; j < 64; ++j) { off[j] = a; a += deg[j]; } off[64] = a; }
    __syncthreads();
    {
      int o = off[l]; const int col = 50 + l;
      for (int base = 0; base < 64; base += 16) {
        float mv[16];
#pragma unroll
        for (int q = 0; q < 16; ++q) mv[q] = smask[(base + q)*UNITS + col];
#pragma unroll
        for (int q = 0; q < 16; ++q)
          if (mv[q] != 0.f) { ePre[o] = (short)(base + q); ePIdx[o] = (short)l; ++o; }
      }
    }
    if (l == 0) {
      int lam = 0, f = 0, pc = 0;
      for (int p = 0; p < 64; ++p) {
        const int dd = deg[p];
        if (pc == 2 || f == CS || dd > 3*CS - f) { ++lam; f = 0; pc = 0; }
        if (lam > 63) lam = 63;
        pLane[p] = lam; pF0[p] = f; pRole[p] = pc;
        ownP[2*lam + pc] = p;
        const int owner = lam, role = pc; ++pc;
        const int take = dd < (CS - f) ? dd : (CS - f);
        f += take; int rem = dd - take;
        if (rem > 0) {
          splitRole[owner] = role; split2[owner] = (rem > CS) ? 1 : 0;
          ++lam; if (lam > 63) lam = 63; contIdx[lam] = 1; contOwn[lam] = owner; pc = 1;
          const int t2 = rem < CS ? rem : CS; f = t2; rem -= t2;
          if (rem > 0) { ++lam; if (lam > 63) lam = 63; contIdx[lam] = 2; contOwn[lam] = owner; pc = 1; f = rem; }
        }
      }
    }
    __syncthreads();
    int dA = (contIdx[l] == 1) ? contOwn[l] : -1;
    int dB = (contIdx[l] == 2) ? contOwn[l] : -1;
    rcv[l] = 0; __syncthreads();
    if (dA >= 0) rcv[dA] = 1;
    __syncthreads();
    { const unsigned long long rM = __ballot(rcv[l] != 0), dM = __ballot(dA < 0);
      if (dA < 0) dA = kthSetBit(~rM, __popcll(dM & ((1ull << l) - 1ull))); }
    __syncthreads();
    rcv[l] = 0; __syncthreads();
    if (dB >= 0) rcv[dB] = 1;
    __syncthreads();
    { const unsigned long long rM = __ballot(rcv[l] != 0), dM = __ballot(dB < 0);
      if (dB < 0) dB = kthSetBit(~rM, __popcll(dM & ((1ull << l) - 1ull))); }
    __syncthreads();
    int rA = (ownP[2*l]   >= 0) ? canonLane(50 + ownP[2*l])   : -1;
    int rB = (ownP[2*l+1] >= 0) ? canonLane(50 + ownP[2*l+1]) : -1;
    rcv[l] = 0; __syncthreads();
    if (rA >= 0) rcv[rA] = 1;
    __syncthreads();
    const int isRcvA = rcv[l];
    { const unsigned long long rM = __ballot(isRcvA != 0), dM = __ballot(rA < 0);
      if (rA < 0) rA = kthSetBit(~rM, __popcll(dM & ((1ull << l) - 1ull))); }
    __syncthreads();
    rcv[l] = 0; __syncthreads();
    if (rB >= 0) rcv[rB] = 1;
    __syncthreads();
    { const unsigned long long rM = __ballot(rcv[l] != 0), dM = __ballot(rB < 0);
      if (rB < 0) rB = kthSetBit(~rM, __popcll(dM & ((1ull << l) - 1ull))); }
    {
      int* M = meta + l * MSTRIDE;
      M[10] = dA * 4; M[11] = dB * 4;
      const float s1A = (splitRole[l] == 0) ? 1.f : 0.f, s1B = (splitRole[l] == 1) ? 1.f : 0.f;
      M[12] = __float_as_int(s1A); M[13] = __float_as_int(s1B);
      const float s2 = split2[l] ? 1.f : 0.f;
      M[14] = __float_as_int(s1A * s2); M[15] = __float_as_int(s1B * s2);
      M[16] = rA * 4; M[17] = rB * 4;
      M[18] = __float_as_int(isRcvA ? 1.f : 0.f);
      M[19] = __float_as_int(isRcvA ? 0.f : 1.f);
      const int pA = ownP[2*l], pB = ownP[2*l+1];
      M[20] = (pA >= 0) ? 50 + pA : 0;
      M[21] = (pB >= 0) ? 50 + pB : 0;
    }
    for (int t = l; t < CS*64; t += 64) {
      senP4[t] = make_float4(0.f,0.f,0.f,0.f); senP2[t] = make_float2(0.f,0.f); senAd[t] = 0;
    }
    __syncthreads();
    {
      const int E = off[64];
      for (int e = l; e < E; e += 64) {
        const int pre = ePre[e], pj = ePIdx[e];
        const int r  = e - off[pj];
        const int dd = deg[pj], f0 = pF0[pj], role0 = pRole[pj];
        const int take = dd < (CS - f0) ? dd : (CS - f0);
        int lane = pLane[pj], slot, role;
        if (r < take)            { slot = f0 + r;        role = role0; }
        else if (r < take + CS)  { lane += 1; slot = r - take;      role = 0; }
        else                     { lane += 2; slot = r - take - CS; role = 0; }
        if (lane > 63) lane = 63;
        const int col = 50 + pj;
        const int idx = pre * UNITS + col;
        const float sg = ssg[idx];
        const float nsgl = -sg * LOG2E, msl = smu[idx] * sg * LOG2E;
        const float wd = sw[idx], wn = wd * serev[idx];
        const int tt = slot * 64 + lane;
        senP4[tt] = make_float4(nsgl, msl, role ? 0.f : wn, role ? 0.f : wd);
        senP2[tt] = role ? make_float2(wn, wd) : make_float2(0.f, 0.f);
        senAd[tt] = pre * 4;
      }
    }
  }
}

// ---------------------------------------------------------------------------
// Run kernel: R9 = R8 structure + software-pipelined sensory. The 6-unfold
// loop is fully unrolled; next-step sensory work (exps, pair-rcps, merges,
// route) is distributed into the unfold compute regions (between wsyncs),
// where the scheduler fills the ~660-cyc stall holes with it. obs prefetched
// 2-3 steps ahead. Triple-shared rcp for rec slots 10-12; paired denominators
// for state-update and sensory-route rcps.
// ---------------------------------------------------------------------------
__global__ __launch_bounds__(64, 2) void ltc_run(
    const float* __restrict__ obs,     const float* __restrict__ hidden,
    const float* __restrict__ input_w, const float* __restrict__ input_b,
    const float* __restrict__ gleak,   const float* __restrict__ vleak,
    const float* __restrict__ cm,
    const float* __restrict__ q_w1, const float* __restrict__ q_b1,
    const float* __restrict__ q_w2, const float* __restrict__ q_b2,
    const float4* __restrict__ recP4, const float2* __restrict__ recP2,
    const int* __restrict__ recAd,
    const float4* __restrict__ senP4, const float2* __restrict__ senP2,
    const int* __restrict__ senAd,
    const int* __restrict__ meta, float* __restrict__ out, int B)
{
  const int l = threadIdx.x, b = blockIdx.x;
  __shared__ float mirror[256];   // [0..113] units, [128..255] scratch sinks
  char* mbase = (char*)mirror;

  float rNS[CR], rMS[CR]; v2f rWA[CR], rWB[CR]; int rad[CR];
#pragma unroll
  for (int s = 0; s < CR; ++s) {
    const float4 p4 = recP4[s*64 + l]; const float2 p2 = recP2[s*64 + l];
    rNS[s] = p4.x; rMS[s] = p4.y; rWA[s] = (v2f){p4.z, p4.w};
    rWB[s] = (v2f){p2.x, p2.y}; rad[s] = recAd[s*64 + l];
  }
  float sNS[CS], sMS[CS]; v2f sWA[CS], sWB[CS]; int sad[CS];
#pragma unroll
  for (int s = 0; s < CS; ++s) {
    const float4 p4 = senP4[s*64 + l]; const float2 p2 = senP2[s*64 + l];
    sNS[s] = p4.x; sMS[s] = p4.y; sWA[s] = (v2f){p4.z, p4.w};
    sWB[s] = (v2f){p2.x, p2.y}; sad[s] = senAd[s*64 + l];
  }

  const int* M = meta + l * MSTRIDE;
  const int   rPush1 = M[0], rPush2 = M[1];
  const v2f gR1A = {__int_as_float(M[2]), __int_as_float(M[2])};
  const v2f gR1B = {__int_as_float(M[3]), __int_as_float(M[3])};
  const v2f gR2A = {__int_as_float(M[4]), __int_as_float(M[4])};
  const v2f gR2B = {__int_as_float(M[5]), __int_as_float(M[5])};
  const int   rWrA = M[6], rWrB = M[7], rUA = M[8], rUB = M[9];
  const int   sPush1 = M[10], sPush2 = M[11];
  const v2f gS1A = {__int_as_float(M[12]), __int_as_float(M[12])};
  const v2f gS1B = {__int_as_float(M[13]), __int_as_float(M[13])};
  const v2f gS2A = {__int_as_float(M[14]), __int_as_float(M[14])};
  const v2f gS2B = {__int_as_float(M[15]), __int_as_float(M[15])};
  const int   sRtA = M[16], sRtB = M[17];
  const float sRndA = __int_as_float(M[18]), sRndB = __int_as_float(M[19]);
  const int   sUA = M[20], sUB = M[21];

  const float cmA  = cm[rUA]*6.f, glvA  = gleak[rUA]*vleak[rUA], cgA  = cm[rUA]*6.f + gleak[rUA] + EPS;
  const float cmB  = cm[rUB]*6.f, glvB  = gleak[rUB]*vleak[rUB], cgB  = cm[rUB]*6.f + gleak[rUB] + EPS;
  const float cmSA = cm[sUA]*6.f, glvSA = gleak[sUA]*vleak[sUA], cgSA = cm[sUA]*6.f + gleak[sUA] + EPS;
  const float cmSB = cm[sUB]*6.f, glvSB = gleak[sUB]*vleak[sUB], cgSB = cm[sUB]*6.f + gleak[sUB] + EPS;

  const int  iUnit = (l < 50) ? 64 + l : l;
  const int  iWr   = iUnit * 4;
  float vIn = hidden[(size_t)b*UNITS + iUnit];
  float vPA = hidden[(size_t)b*UNITS + rUA];
  float vPB = hidden[(size_t)b*UNITS + rUB];

  mirror[l] = hidden[(size_t)b*UNITS + l];
  if (l < 50) mirror[64 + l] = hidden[(size_t)b*UNITS + 64 + l];

  const float iw = input_w[l], ibv = input_b[l];
  const float* ob = obs + (size_t)b*(TSTEPS*SDIM) + l;

  // ---- prologue: full sensory eval for t=0 (R8 code path) ----
  float aI, bI;
  {
    const float xi = fmaf(ob[0], iw, ibv);
    float uu[CS];
#pragma unroll
    for (int s = 0; s < CS; ++s) {
      float z = fmaf(bperm(sad[s], xi), sNS[s], sMS[s]);
      z = fminf(z, 30.f);
      uu[s] = 1.f + __builtin_amdgcn_exp2f(z);
    }
    float sg[CS];
#pragma unroll
    for (int q = 0; q < 4; ++q) {
      const float p = uu[2*q] * uu[2*q+1];
      const float r = __builtin_amdgcn_rcpf(p);
      sg[2*q]   = uu[2*q+1] * r;
      sg[2*q+1] = uu[2*q]   * r;
    }
    sg[8] = __builtin_amdgcn_rcpf(uu[8]);
    v2f cA = {0.f,0.f}, cB = {0.f,0.f};
#pragma unroll
    for (int s = 0; s < CS; ++s) {
      const v2f s2 = {sg[s], sg[s]};
      cA = fma2(sWA[s], s2, cA);
      cB = fma2(sWB[s], s2, cB);
    }
    const v2f m1 = {dperm(sPush1, cA.x), dperm(sPush1, cA.y)};
    const v2f m2 = {dperm(sPush2, cA.x), dperm(sPush2, cA.y)};
    v2f tA = fma2(gS1A, m1, cA); tA = fma2(gS2A, m2, tA);
    v2f tB = fma2(gS1B, m1, cB); tB = fma2(gS2B, m2, tB);
    const float rdA = __builtin_amdgcn_rcpf(cgSA + tA.y);
    const float aA = cmSA * rdA, bA = (glvSA + tA.x) * rdA;
    const float rdB = __builtin_amdgcn_rcpf(cgSB + tB.y);
    const float aB = cmSB * rdB, bB = (glvSB + tB.x) * rdB;
    const float ra1 = dperm(sRtA, aA), rb1 = dperm(sRtA, bA);
    const float ra2 = dperm(sRtB, aB), rb2 = dperm(sRtB, bB);
    aI = sRndA*ra1 + sRndB*ra2;
    bI = sRndA*rb1 + sRndB*rb2;
  }

  // pipeline state for next-step sensory
  float xiN = fmaf(ob[SDIM], iw, ibv);   // xi(1)
  float xrC = ob[2*SDIM];                // obs(2)
  float su[CS];
  v2f acA = {0.f,0.f}, acB = {0.f,0.f};
  v2f tSA = {0.f,0.f}, tSB = {0.f,0.f};
  float aIn = 0.f, bIn = 0.f;

  // one rec unfold with an embedded chunk of next-step sensory work
  auto unfold = [&](auto chunk) {
    wsync();
    float uu[CR];
#pragma unroll
    for (int s = 0; s < CR; ++s) {
      const float pv = *(const float*)(mbase + rad[s]);
      float z = fmaf(pv, rNS[s], rMS[s]);
      z = fminf(z, 30.f);
      uu[s] = 1.f + __builtin_amdgcn_exp2f(z);
    }
    chunk();                    // independent sensory work fills stalls here
    float sg[CR];
#pragma unroll
    for (int q = 0; q < 5; ++q) {
      const float p = uu[2*q] * uu[2*q+1];
      const float r = __builtin_amdgcn_rcpf(p);
      sg[2*q]   = uu[2*q+1] * r;
      sg[2*q+1] = uu[2*q]   * r;
    }
    {   // triple-shared rcp for slots 10,11,12
      const float p01 = uu[10]*uu[11];
      const float r = __builtin_amdgcn_rcpf(p01*uu[12]);
      const float t12 = uu[12]*r;
      sg[10] = uu[11]*t12; sg[11] = uu[10]*t12; sg[12] = p01*r;
    }
    v2f a0 = {0.f,0.f}, a1 = {0.f,0.f}, b0 = {0.f,0.f}, b1 = {0.f,0.f};
#pragma unroll
    for (int s = 0; s < CR; ++s) {
      const v2f s2 = {sg[s], sg[s]};
      if (s & 1) { a1 = fma2(rWA[s], s2, a1); b1 = fma2(rWB[s], s2, b1); }
      else       { a0 = fma2(rWA[s], s2, a0); b0 = fma2(rWB[s], s2, b0); }
    }
    v2f aA = a0 + a1, aB = b0 + b1;
    const v2f m1 = {dperm(rPush1, aA.x), dperm(rPush1, aA.y)};
    const v2f m2 = {dperm(rPush2, aA.x), dperm(rPush2, aA.y)};
    v2f tA = fma2(gR1A, m1, aA); tA = fma2(gR2A, m2, tA);
    v2f tB = fma2(gR1B, m1, aB); tB = fma2(gR2B, m2, tB);
    const float dAq = cgA + tA.y, dBq = cgB + tB.y;
    const float rr = __builtin_amdgcn_rcpf(dAq * dBq);    // paired rcp
    vPA = (fmaf(cmA, vPA, glvA) + tA.x) * (dBq * rr);
    vPB = (fmaf(cmB, vPB, glvB) + tB.x) * (dAq * rr);
    vIn = fmaf(aI, vIn, bI);
    wsync();
    *(float*)(mbase + rWrA) = vPA;
    *(float*)(mbase + rWrB) = vPB;
    *(float*)(mbase + iWr)  = vIn;
  };

  auto sExp = [&](int s) {
    float z = fmaf(bperm(sad[s], xiN), sNS[s], sMS[s]);
    z = fminf(z, 30.f);
    su[s] = 1.f + __builtin_amdgcn_exp2f(z);
  };
  auto sPair = [&](int s0) {
    const float p = su[s0] * su[s0+1];
    const float r = __builtin_amdgcn_rcpf(p);
    const float g0 = su[s0+1] * r, g1 = su[s0] * r;
    acA = fma2(sWA[s0],   (v2f){g0,g0}, acA);
    acA = fma2(sWA[s0+1], (v2f){g1,g1}, acA);
    acB = fma2(sWB[s0],   (v2f){g0,g0}, acB);
    acB = fma2(sWB[s0+1], (v2f){g1,g1}, acB);
  };

#pragma unroll 1
  for (int t = 0; t < TSTEPS; ++t) {
    unfold([&]{ sExp(0); sExp(1); });
    unfold([&]{ sExp(2); sExp(3); sPair(0); });
    unfold([&]{ sExp(4); sExp(5); sPair(2); });
    unfold([&]{ sExp(6); sExp(7); sExp(8); sPair(4); });
    unfold([&]{
      // triple-shared rcp for sensory slots 6,7,8 + accumulate + merge
      const float p67 = su[6] * su[7];
      const float r = __builtin_amdgcn_rcpf(p67 * su[8]);
      const float t67 = su[8] * r;
      const float g6 = su[7]*t67, g7 = su[6]*t67, g8 = p67*r;
      acA = fma2(sWA[6], (v2f){g6,g6}, acA); acB = fma2(sWB[6], (v2f){g6,g6}, acB);
      acA = fma2(sWA[7], (v2f){g7,g7}, acA); acB = fma2(sWB[7], (v2f){g7,g7}, acB);
      acA = fma2(sWA[8], (v2f){g8,g8}, acA); acB = fma2(sWB[8], (v2f){g8,g8}, acB);
      const v2f m1 = {dperm(sPush1, acA.x), dperm(sPush1, acA.y)};
      const v2f m2 = {dperm(sPush2, acA.x), dperm(sPush2, acA.y)};
      tSA = fma2(gS1A, m1, acA); tSA = fma2(gS2A, m2, tSA);
      tSB = fma2(gS1B, m1, acB); tSB = fma2(gS2B, m2, tSB);
    });
    unfold([&]{
      // route (aI,bI) for next step to canonical lanes
      const float dA_ = cgSA + tSA.y, dB_ = cgSB + tSB.y;
      const float rr = __builtin_amdgcn_rcpf(dA_ * dB_);   // paired rcp
      const float rdA = dB_ * rr, rdB = dA_ * rr;
      const float aA = cmSA * rdA, bA = (glvSA + tSA.x) * rdA;
      const float aB = cmSB * rdB, bB = (glvSB + tSB.x) * rdB;
      const float ra1 = dperm(sRtA, aA), rb1 = dperm(sRtA, bA);
      const float ra2 = dperm(sRtB, aB), rb2 = dperm(sRtB, bB);
      aIn = sRndA*ra1 + sRndB*ra2;
      bIn = sRndA*rb1 + sRndB*rb2;
    });
    // step boundary: rotate pipeline state
    aI = aIn; bI = bIn;
    xiN = fmaf(xrC, iw, ibv);                      // xi(t+2)
    const int tn = (t + 3 < TSTEPS) ? (t + 3) : (TSTEPS - 1);
    xrC = ob[tn * SDIM];                           // obs(t+3), clamped
    acA = (v2f){0.f,0.f}; acB = (v2f){0.f,0.f};
  }
  wsync();

  // ---- outputs: h then Q head ----
  float* __restrict__ outH = out + (size_t)B * ACT;
  outH[(size_t)b*UNITS + l] = mirror[l];
  if (l < 50) outH[(size_t)b*UNITS + 64 + l] = mirror[64 + l];

  const int j2 = (l < 50) ? 64 + l : l;
  float h1 = q_b1[l], h2 = q_b1[j2];
  for (int i = 0; i < UNITS; ++i) {
    const float hv = mirror[i];
    h1 = fmaf(hv, q_w1[i*UNITS + l],  h1);
    h2 = fmaf(hv, q_w1[i*UNITS + j2], h2);
  }
  h1 = fmaxf(h1, 0.f); h2 = fmaxf(h2, 0.f);
  wsync();
  mirror[l] = h1;
  if (l < 50) mirror[64 + l] = h2;
  wsync();
  if (l < ACT) {
    float q = q_b2[l];
    for (int i = 0; i < UNITS; ++i) q = fmaf(mirror[i], q_w2[i*ACT + l], q);
    out[(size_t)b*ACT + l] = q;
  }
}

extern "C" void kernel_launch(void* const* d_in, const int* in_sizes, int n_in,
                              void* d_out, int out_size, void* d_ws, size_t ws_size,
                              hipStream_t stream)
{
  const float* obs           = (const float*)d_in[0];
  const float* hidden        = (const float*)d_in[1];
  const float* input_w       = (const float*)d_in[2];
  const float* input_b       = (const float*)d_in[3];
  const float* sensory_w     = (const float*)d_in[4];
  const float* sensory_mu    = (const float*)d_in[5];
  const float* sensory_sigma = (const float*)d_in[6];
  const float* sensory_erev  = (const float*)d_in[7];
  const float* sensory_mask  = (const float*)d_in[8];
  const float* w             = (const float*)d_in[9];
  const float* mu            = (const float*)d_in[10];
  const float* sigma         = (const float*)d_in[11];
  const float* erev          = (const float*)d_in[12];
  const float* mask          = (const float*)d_in[13];
  const float* gleak         = (const float*)d_in[14];
  const float* vleak         = (const float*)d_in[15];
  const float* cm            = (const float*)d_in[16];
  const float* q_w1          = (const float*)d_in[17];
  const float* q_b1          = (const float*)d_in[18];
  const float* q_w2          = (const float*)d_in[19];
  const float* q_b2          = (const float*)d_in[20];

  char* ws = (char*)d_ws;
  float4* recP4 = (float4*)(ws);            // 13*64*16 = 13312
  float2* recP2 = (float2*)(ws + 13312);    // 13*64*8  = 6656  -> 19968
  int*    recAd = (int*)   (ws + 19968);    // 13*64*4  = 3328  -> 23296
  float4* senP4 = (float4*)(ws + 23296);    // 9*64*16  = 9216  -> 32512
  float2* senP2 = (float2*)(ws + 32512);    // 9*64*8   = 4608  -> 37120
  int*    senAd = (int*)   (ws + 37120);    // 9*64*4   = 2304  -> 39424
  int*    meta  = (int*)   (ws + 39424);    // 64*24*4  = 6144  -> 45568

  build_all<<<2, 64, 0, stream>>>(
      w, mu, sigma, erev, mask,
      sensory_w, sensory_mu, sensory_sigma, sensory_erev, sensory_mask,
      recP4, recP2, recAd, senP4, senP2, senAd, meta);

  const int B = in_sizes[0] / (TSTEPS * SDIM);
  ltc_run<<<B, 64, 0, stream>>>(
      obs, hidden, input_w, input_b, gleak, vleak, cm,
      q_w1, q_b1, q_w2, q_b2,
      recP4, recP2, recAd, senP4, senP2, senAd, meta,
      (float*)d_out, B);
}